// Round 8
// baseline (180.764 us; speedup 1.0000x reference)
//
#include <hip/hip_runtime.h>
#include <cstdint>

typedef unsigned short u16;
typedef __bf16 bf16x8 __attribute__((ext_vector_type(8)));
typedef __bf16 bf16x2 __attribute__((ext_vector_type(2)));
typedef float floatx4 __attribute__((ext_vector_type(4)));
typedef unsigned short u16x4 __attribute__((ext_vector_type(4)));
typedef unsigned short u16x8 __attribute__((ext_vector_type(8)));

#define MFMA16(a, b, c) __builtin_amdgcn_mfma_f32_16x16x32_bf16((a), (b), (c), 0, 0, 0)
// 0.125 * log2(e): folded into Q so softmax is exp2(st) with no per-elem mul.
#define QSCALE_LOG2E 0.18033688011112042f

// ---- helpers -------------------------------------------------------------

typedef __attribute__((address_space(3))) void as3_void;
typedef __attribute__((address_space(1))) void as1_void;

static __device__ __forceinline__ void async_load16(const void* g, void* l) {
  __builtin_amdgcn_global_load_lds((as1_void*)(uintptr_t)g, (as3_void*)(uintptr_t)l,
                                   16, 0, 0);
}

static __device__ __forceinline__ u16 f2bf(float f) {
  union { float f; unsigned int u; } v; v.f = f;
  unsigned int u = v.u;
  u += 0x7fffu + ((u >> 16) & 1u);   // RNE
  return (u16)(u >> 16);
}

static __device__ __forceinline__ u16x4 pack_bf4(float a, float b, float c, float d) {
#if __has_builtin(__builtin_amdgcn_cvt_pk_bf16_f32)
  union { u16x4 v4; bf16x2 v2[2]; } u;
  u.v2[0] = __builtin_amdgcn_cvt_pk_bf16_f32(a, b);
  u.v2[1] = __builtin_amdgcn_cvt_pk_bf16_f32(c, d);
  return u.v4;
#else
  u16x4 r; r[0] = f2bf(a); r[1] = f2bf(b); r[2] = f2bf(c); r[3] = f2bf(d);
  return r;
#endif
}

static __device__ __forceinline__ unsigned pack_bf2(float a, float b) {
#if __has_builtin(__builtin_amdgcn_cvt_pk_bf16_f32)
  union { bf16x2 v; unsigned u; } x;
  x.v = __builtin_amdgcn_cvt_pk_bf16_f32(a, b);
  return x.u;
#else
  return (unsigned)f2bf(a) | ((unsigned)f2bf(b) << 16);
#endif
}

static __device__ __forceinline__ float fast_exp2(float x) {
#if __has_builtin(__builtin_amdgcn_exp2f)
  return __builtin_amdgcn_exp2f(x);
#else
  return exp2f(x);
#endif
}

// ---- fused: 4x weight transpose+convert (z=0..3) + x convert (z=4) -------

__global__ __launch_bounds__(256) void prep_kernel(
    const float* __restrict__ w0, const float* __restrict__ w1,
    const float* __restrict__ w2, const float* __restrict__ w3,
    u16* __restrict__ wout,
    const float* __restrict__ xin, u16* __restrict__ xout) {
  if (blockIdx.z == 4) {
    int blk = blockIdx.y * 16 + blockIdx.x;
    size_t base = (size_t)blk * 16384 + (size_t)threadIdx.x * 8;
#pragma unroll
    for (int r = 0; r < 8; r++) {
      size_t i = base + (size_t)r * 2048;
      float4 a = *(const float4*)(xin + i);
      float4 b = *(const float4*)(xin + i + 4);
      u16x8 o;
      o[0] = f2bf(a.x); o[1] = f2bf(a.y); o[2] = f2bf(a.z); o[3] = f2bf(a.w);
      o[4] = f2bf(b.x); o[5] = f2bf(b.y); o[6] = f2bf(b.z); o[7] = f2bf(b.w);
      *(u16x8*)(xout + i) = o;
    }
    return;
  }
  __shared__ u16 t[64][65];
  const float* in = (blockIdx.z == 0) ? w0 : (blockIdx.z == 1) ? w1
                    : (blockIdx.z == 2) ? w2 : w3;
  u16* oz = wout + (size_t)blockIdx.z * (1024 * 1024);
  const int tid = threadIdx.x;
  const int x = tid & 63, y0 = tid >> 6;
  const int bx = blockIdx.x * 64, by = blockIdx.y * 64;
#pragma unroll
  for (int p = 0; p < 16; p++) {
    int y = y0 + p * 4;
    t[y][x] = f2bf(in[(size_t)(by + y) * 1024 + bx + x]);
  }
  __syncthreads();
#pragma unroll
  for (int p = 0; p < 16; p++) {
    int r = y0 + p * 4;
    oz[(size_t)(bx + r) * 1024 + by + x] = t[x][r];
  }
}

// ---- QKV GEMM: C[4096][1024] = X @ Wz, Wz given transposed [N][K] --------
// 128x128 tile, BK=32, 4 waves, global_load_lds staging, XOR-swizzled octets.
// Double-buffered As/Bs + raw-barrier loop (R12); tb aliases the arena (R15,
// 32 KB/block -> up to 4-5 blocks/CU).
// z==0 (Q): pre-scaled by QSCALE_LOG2E.  z==1 (K).  z==2 (V): V^T epilogue.

__global__ __launch_bounds__(256, 3) void gemm_qkv_kernel(
    const u16* __restrict__ A, const u16* __restrict__ BT,
    u16* __restrict__ out, u16* __restrict__ outVT) {
  __shared__ __align__(16) u16 sm[2 * 4096 + 2 * 4096];   // 32 KB arena
  u16* As = sm;                      // 2 x 8 KB
  u16* Bs = sm + 2 * 4096;           // 2 x 8 KB
  u16* tb = sm;                      // 64*136 u16 = 17 KB, aliases As+Bs[0..]
  const int tid = threadIdx.x;
  const int w = tid >> 6, lane = tid & 63;
  const int bm = blockIdx.y * 128, bn = blockIdx.x * 128;
  const int z = blockIdx.z;
  const int K = 1024, N = 1024;
  const u16* Bz = BT + (size_t)z * N * K;

  const int c0 = w * 2, c1 = c0 + 1;
  const int mA0 = c0 * 16 + (lane >> 2), mA1 = c1 * 16 + (lane >> 2);
  const int kg0 = (lane & 3) ^ ((mA0 >> 1) & 3);
  const int kg1 = (lane & 3) ^ ((mA1 >> 1) & 3);
  const u16* agp0 = A + (size_t)(bm + mA0) * K + kg0 * 8;
  const u16* agp1 = A + (size_t)(bm + mA1) * K + kg1 * 8;
  const u16* bgp0 = Bz + (size_t)(bn + mA0) * K + kg0 * 8;
  const u16* bgp1 = Bz + (size_t)(bn + mA1) * K + kg1 * 8;

  const int wm = (w >> 1) * 64, wn = (w & 1) * 64;
  floatx4 acc[4][4] = {};

  int a_off[4], b_off[4];
#pragma unroll
  for (int i = 0; i < 4; i++) {
    int m = wm + i * 16 + (lane & 15);
    a_off[i] = m * 32 + (((lane >> 4) ^ ((m >> 1) & 3)) * 8);
    int n = wn + i * 16 + (lane & 15);
    b_off[i] = n * 32 + (((lane >> 4) ^ ((n >> 1) & 3)) * 8);
  }

  auto issueQ = [&](int buf, int k0) {
    u16* ab = As + buf * 4096;
    u16* bb = Bs + buf * 4096;
    async_load16(agp0 + k0, ab + c0 * 512);
    async_load16(agp1 + k0, ab + c1 * 512);
    async_load16(bgp0 + k0, bb + c0 * 512);
    async_load16(bgp1 + k0, bb + c1 * 512);
  };

  issueQ(0, 0);
  asm volatile("s_waitcnt vmcnt(0)" ::: "memory");
  __builtin_amdgcn_s_barrier();

#pragma unroll 2
  for (int kk = 0; kk < 32; ++kk) {
    if (kk < 31) issueQ((kk + 1) & 1, (kk + 1) * 32);
    const u16* Ab = As + (kk & 1) * 4096;
    const u16* Bb = Bs + (kk & 1) * 4096;
    bf16x8 af[4], bf[4];
#pragma unroll
    for (int i = 0; i < 4; i++) af[i] = *(const bf16x8*)(Ab + a_off[i]);
#pragma unroll
    for (int j = 0; j < 4; j++) bf[j] = *(const bf16x8*)(Bb + b_off[j]);
    __builtin_amdgcn_s_setprio(1);
#pragma unroll
    for (int i = 0; i < 4; i++)
#pragma unroll
      for (int j = 0; j < 4; j++)
        acc[i][j] = MFMA16(af[i], bf[j], acc[i][j]);
    __builtin_amdgcn_s_setprio(0);
    // own loads for kk+1 landed + own reads of this buf done, then converge
    asm volatile("s_waitcnt vmcnt(0) lgkmcnt(0)" ::: "memory");
    __builtin_amdgcn_s_barrier();
  }

  // epilogue: C/D layout col=lane&15, row=(lane>>4)*4+reg  [m89]
  const int roff = (lane >> 4) * 4;
  const int coff = lane & 15;
  if (z == 2) {
    // V^T: two 64-col halves through padded LDS, then coalesced b128 stores
    const int b = bm >> 11, s0 = bm & 2047;
#pragma unroll
    for (int half = 0; half < 2; half++) {
      __syncthreads();
      if ((w & 1) == half) {
#pragma unroll
        for (int i = 0; i < 4; i++) {
          int s_local = wm + i * 16 + roff;
#pragma unroll
          for (int j = 0; j < 4; j++) {
            int c_local = j * 16 + coff;     // 0..63 within half
            u16x4 pk = pack_bf4(acc[i][j][0], acc[i][j][1],
                                acc[i][j][2], acc[i][j][3]);
            *(u16x4*)(tb + c_local * 136 + s_local) = pk;
          }
        }
      }
      __syncthreads();
      // store: 16 consecutive lanes cover one d-row's 128 s (256B contiguous)
#pragma unroll
      for (int p = 0; p < 4; p++) {
        int c_local = (tid >> 4) & 15;       // 0..15
        int row = p * 16 + c_local;          // 0..63
        int so = tid & 15;
        int cg = bn + half * 64 + row;
        int h = cg >> 6, d = cg & 63;
        u16x8 vv = *(const u16x8*)(tb + row * 136 + so * 8);
        *(u16x8*)(outVT + ((size_t)(b * 16 + h) * 64 + d) * 2048 + s0 + so * 8) = vv;
      }
    }
  } else {
    const float sc = (z == 0) ? QSCALE_LOG2E : 1.0f;
    u16* outz = out + (size_t)z * 4096 * 1024;
#pragma unroll
    for (int i = 0; i < 4; i++) {
      int r0 = bm + wm + i * 16 + roff;
#pragma unroll
      for (int j = 0; j < 4; j++) {
        int c = bn + wn + j * 16 + coff;
#pragma unroll
        for (int r = 0; r < 4; r++)
          outz[(size_t)(r0 + r) * N + c] = f2bf(acc[i][j][r] * sc);
      }
    }
  }
}

// ---- O GEMM: out[4096][1024] f32 = CTX @ Wo + bo -------------------------
// R16: 64x64 tile, BK=32, 4 waves (2x2 of 32x32) -> 1024 blocks = 4/CU.
// The old 128x64 tiling gave 512 blocks = 2 blocks/CU = 2 waves/SIMD (25%
// occupancy) — latency-exposed K-loop.  64x64 doubles TLP to 4 waves/SIMD;
// acc[2][2]=16 VGPR keeps total ~75 regs, far under the 128 cap of
// __launch_bounds__(256,4) — no spill risk.  Same dbuf + raw-barrier
// structure and XOR-swizzle addressing as gemm_qkv.

__global__ __launch_bounds__(256, 4) void gemm_o_kernel(
    const u16* __restrict__ A, const u16* __restrict__ BT,
    const float* __restrict__ bias, float* __restrict__ out) {
  __shared__ u16 As[2 * 2048];       // 64x32 per buffer
  __shared__ u16 Bs[2 * 2048];
  const int tid = threadIdx.x;
  const int w = tid >> 6, lane = tid & 63;
  const int bm = blockIdx.y * 64, bn = blockIdx.x * 64;
  const int K = 1024, N = 1024;

  // staging: 8 chunks of 16 rows (0-3 = A rows, 4-7 = B rows); wave w owns
  // chunks {2w, 2w+1}; global src pre-swizzled to match fragment slots.
  const u16* gp[2];
  int lo[2];                         // chunk LDS offset (u16) within buffer
  bool isB[2];
#pragma unroll
  for (int i = 0; i < 2; i++) {
    int c = w * 2 + i;
    if (c < 4) {
      int m = c * 16 + (lane >> 2);
      int kg = (lane & 3) ^ ((m >> 1) & 3);
      gp[i] = A + (size_t)(bm + m) * K + kg * 8;
      lo[i] = c * 512;
      isB[i] = false;
    } else {
      int cb = c - 4;
      int n = cb * 16 + (lane >> 2);
      int kg = (lane & 3) ^ ((n >> 1) & 3);
      gp[i] = BT + (size_t)(bn + n) * K + kg * 8;
      lo[i] = cb * 512;
      isB[i] = true;
    }
  }

  const int wm = (w >> 1) * 32, wn = (w & 1) * 32;
  floatx4 acc[2][2] = {};

  int a_off[2], b_off[2];
#pragma unroll
  for (int i = 0; i < 2; i++) {
    int m = wm + i * 16 + (lane & 15);
    a_off[i] = m * 32 + (((lane >> 4) ^ ((m >> 1) & 3)) * 8);
    int n = wn + i * 16 + (lane & 15);
    b_off[i] = n * 32 + (((lane >> 4) ^ ((n >> 1) & 3)) * 8);
  }

  auto issueO = [&](int buf, int k0) {
#pragma unroll
    for (int i = 0; i < 2; i++) {
      u16* dst = (isB[i] ? Bs : As) + buf * 2048 + lo[i];
      async_load16(gp[i] + k0, dst);
    }
  };

  issueO(0, 0);
  asm volatile("s_waitcnt vmcnt(0)" ::: "memory");
  __builtin_amdgcn_s_barrier();

#pragma unroll 2
  for (int kk = 0; kk < 32; ++kk) {
    if (kk < 31) issueO((kk + 1) & 1, (kk + 1) * 32);
    const u16* Ab = As + (kk & 1) * 2048;
    const u16* Bb = Bs + (kk & 1) * 2048;
    bf16x8 af[2], bf[2];
#pragma unroll
    for (int i = 0; i < 2; i++) af[i] = *(const bf16x8*)(Ab + a_off[i]);
#pragma unroll
    for (int j = 0; j < 2; j++) bf[j] = *(const bf16x8*)(Bb + b_off[j]);
    __builtin_amdgcn_s_setprio(1);
#pragma unroll
    for (int i = 0; i < 2; i++)
#pragma unroll
      for (int j = 0; j < 2; j++)
        acc[i][j] = MFMA16(af[i], bf[j], acc[i][j]);
    __builtin_amdgcn_s_setprio(0);
    asm volatile("s_waitcnt vmcnt(0) lgkmcnt(0)" ::: "memory");
    __builtin_amdgcn_s_barrier();
  }

  const int roff = (lane >> 4) * 4;
  const int coff = lane & 15;
#pragma unroll
  for (int i = 0; i < 2; i++) {
    int r0 = bm + wm + i * 16 + roff;
#pragma unroll
    for (int j = 0; j < 2; j++) {
      int c = bn + wn + j * 16 + coff;
      float bv = bias[c];
#pragma unroll
      for (int r = 0; r < 4; r++)
        out[(size_t)(r0 + r) * N + c] = acc[i][j][r] + bv;
    }
  }
}

// ---- flash attention (no-max softmax, 512-thread blocks, s-split pairs) --
// Q (pre-scaled), K: [b*2048+s][1024] row-major bf16, head at col h*64.
// VT: [bh][64][2048] bf16.  ctx: [b][s][1024] bf16.
// Block = 8 waves over a 128q x 128s tile: wave (qq,sh) = q-quarter qq
// (32 rows in registers as B-operand) x s-half sh (64 cols).
//
// Verified at 50.6-51.1 us.  R12/R13/R14 pipeline-deepening all spilled:
// per-wave state ~120 regs on the UNIFIED gfx950 VGPR/AGPR file caps
// occupancy at 4 waves/SIMD; do not add live state across the QK phase.
// setprio retained (neutral, m190-consistent: barrier-lockstep).
// In-register P (permlane16_swap, sigma=(0,2,1,3) absorbed into vf slot);
// K/V double-buffered, one raw barrier + one vmcnt(0) per iteration.

__global__ __launch_bounds__(512, 4) void attn_kernel(
    const u16* __restrict__ Q, const u16* __restrict__ Kx,
    const u16* __restrict__ VT, u16* __restrict__ ctx) {
  // arena: 2 x { Ks [128s][64d] | Vs [64d][128s] } = 64 KB
  __shared__ __align__(16) u16 lds[32768];
  const int tid = threadIdx.x;
  const int w = tid >> 6, lane = tid & 63;
  const int qq = w >> 1, sh = w & 1;
  const int quad = lane >> 4;
  const int bid = blockIdx.x;
  const int bh = (bid >> 7) * 8 + (bid & 7);      // XCD-pinned head group
  const int q0 = ((bid >> 3) & 15) * 128;
  const int b = bh >> 4, h = bh & 15;
  const u16* Qh = Q + (size_t)b * 2048 * 1024 + h * 64;
  const u16* Kh = Kx + (size_t)b * 2048 * 1024 + h * 64;
  const u16* Vh = VT + (size_t)bh * 64 * 2048;

  // staging: wave w owns Ks chunks {2w,2w+1} and Vs chunks {2w,2w+1}
  const u16* kgp[2]; const u16* vgp[2];
  int kc[2], vc[2];
#pragma unroll
  for (int i = 0; i < 2; i++) {
    int c = w * 2 + i;                 // 0..15
    int sl = c * 8 + (lane >> 3);
    int dg = (lane & 7) ^ (lane >> 3);
    kgp[i] = Kh + (size_t)sl * 1024 + dg * 8;
    kc[i] = c * 512;
    int dl = c * 4 + quad;
    int sg = (lane & 15) ^ (dl & 15);
    vgp[i] = Vh + (size_t)dl * 2048 + sg * 8;
    vc[i] = 8192 + c * 512;
  }

  auto issue_tile = [&](int buf, int t) {
    u16* dst = lds + buf * 16384;
    const size_t k0 = (size_t)t * 128;
#pragma unroll
    for (int i = 0; i < 2; i++) {
      async_load16(kgp[i] + k0 * 1024, dst + kc[i]);
      async_load16(vgp[i] + k0, dst + vc[i]);
    }
  };

  issue_tile(0, 0);                    // tile 0 loads overlap Q-frag loads

  // Q fragments: 32 q-rows/wave (B-operand: col=lane&15, k-octet=quad)
  const int qbase = q0 + qq * 32;
  bf16x8 qf[2][2];
#pragma unroll
  for (int qt = 0; qt < 2; qt++)
#pragma unroll
    for (int ks = 0; ks < 2; ks++)
      qf[qt][ks] = *(const bf16x8*)(Qh + (size_t)(qbase + qt * 16 + (lane & 15)) * 1024 +
                                    ks * 32 + quad * 8);

  bf16x8 onesf;
#pragma unroll
  for (int i = 0; i < 8; i++) onesf[i] = (__bf16)1.0f;
  const floatx4 zero4 = {};

  // K-fragment LDS offsets for this wave's s-half (4 slabs of 16 s)
  const int slot_k0 = quad ^ (lane & 7);
  const int slot_k1 = (4 + quad) ^ (lane & 7);
  const int koff0 = sh * 4096 + (lane & 15) * 64 + slot_k0 * 8;
  const int koff1 = sh * 4096 + (lane & 15) * 64 + slot_k1 * 8;
  // V-fragment offsets: MFMA k-octet Q holds s-octet sigma(Q)=bitrev2(Q)
  const int sq = ((quad & 1) << 1) | (quad >> 1);

  floatx4 o[2][4] = {};
  floatx4 lacc[2] = {};              // partial row sums (this s-half)

  // drain qf + tile-0 staging once so the loop's vmcnt discipline is clean
  asm volatile("s_waitcnt vmcnt(0)" ::: "memory");

#pragma unroll 2
  for (int t = 0; t < 16; ++t) {
    __builtin_amdgcn_s_barrier();        // tile t visible to all waves
    __builtin_amdgcn_sched_barrier(0);
    if (t < 15) issue_tile((t + 1) & 1, t + 1);   // in flight across compute
    const u16* Ksb = lds + (t & 1) * 16384;
    const u16* Vsb = Ksb + 8192;

    // QK for this wave's 4 slabs (batched: 16 MFMAs in flight)
    floatx4 st[4][2];
    __builtin_amdgcn_s_setprio(1);
#pragma unroll
    for (int si = 0; si < 4; si++) {
      bf16x8 kf0 = *(const bf16x8*)(Ksb + koff0 + si * 1024);
      bf16x8 kf1 = *(const bf16x8*)(Ksb + koff1 + si * 1024);
#pragma unroll
      for (int qt = 0; qt < 2; qt++)
        st[si][qt] = MFMA16(kf1, qf[qt][1], MFMA16(kf0, qf[qt][0], zero4));
    }
    __builtin_amdgcn_s_setprio(0);

    // p = exp2(st), pack to bf16 pairs: pa = regs{0,1}, pb = regs{2,3}
    unsigned pa[2][4], pb[2][4];
#pragma unroll
    for (int si = 0; si < 4; si++)
#pragma unroll
      for (int qt = 0; qt < 2; qt++) {
        pa[qt][si] = pack_bf2(fast_exp2(st[si][qt][0]), fast_exp2(st[si][qt][1]));
        pb[qt][si] = pack_bf2(fast_exp2(st[si][qt][2]), fast_exp2(st[si][qt][3]));
      }

    // in-register P->A-operand: swap quad pairs; resulting k-octet order is
    // sigma = (0,2,1,3), matched by the vf slot below.
    bf16x8 pf[2][2];
#pragma unroll
    for (int qt = 0; qt < 2; qt++)
#pragma unroll
      for (int ksl = 0; ksl < 2; ksl++) {
        unsigned x0 = pa[qt][2 * ksl], x1 = pa[qt][2 * ksl + 1];
        unsigned y0 = pb[qt][2 * ksl], y1 = pb[qt][2 * ksl + 1];
        asm("v_permlane16_swap_b32 %0, %1" : "+v"(x0), "+v"(x1));
        asm("v_permlane16_swap_b32 %0, %1" : "+v"(y0), "+v"(y1));
        union { unsigned u[4]; bf16x8 v; } uu;
        uu.u[0] = x0; uu.u[1] = y0; uu.u[2] = x1; uu.u[3] = y1;
        pf[qt][ksl] = uu.v;
      }

    // O += P . V over this s-half's two 32-s blocks
    __builtin_amdgcn_s_setprio(1);
#pragma unroll
    for (int ksl = 0; ksl < 2; ksl++) {
      int kb = sh * 2 + ksl;
      bf16x8 vf[4];
#pragma unroll
      for (int jt = 0; jt < 4; jt++) {
        int d = jt * 16 + (lane & 15);
        int slot = (kb * 4 + sq) ^ (d & 15);
        vf[jt] = *(const bf16x8*)(Vsb + d * 128 + slot * 8);
      }
#pragma unroll
      for (int qt = 0; qt < 2; qt++) {
#pragma unroll
        for (int jt = 0; jt < 4; jt++)
          o[qt][jt] = MFMA16(pf[qt][ksl], vf[jt], o[qt][jt]);
        lacc[qt] = MFMA16(pf[qt][ksl], onesf, lacc[qt]);
      }
    }
    __builtin_amdgcn_s_setprio(0);
    // own tile-(t+1) loads must be done before the next barrier
    asm volatile("s_waitcnt vmcnt(0)" ::: "memory");
  }

  // combine s-halves: sh==1 dumps O,l; sh==0 adds + stores.
  // dump region = lds[0..32KB) for O (2048 floatx4), [32KB..40KB) for l.
  __syncthreads();
  floatx4* dump  = (floatx4*)lds;
  floatx4* ldump = (floatx4*)(lds + 16384);
  if (sh == 1) {
    int base = qq * 512;
#pragma unroll
    for (int qt = 0; qt < 2; qt++)
#pragma unroll
      for (int jt = 0; jt < 4; jt++)
        dump[base + (qt * 4 + jt) * 64 + lane] = o[qt][jt];
#pragma unroll
    for (int qt = 0; qt < 2; qt++)
      ldump[qq * 128 + qt * 64 + lane] = lacc[qt];
  }
  __syncthreads();
  if (sh == 0) {
    int base = qq * 512;
#pragma unroll
    for (int qt = 0; qt < 2; qt++)
#pragma unroll
      for (int jt = 0; jt < 4; jt++)
        o[qt][jt] += dump[base + (qt * 4 + jt) * 64 + lane];
#pragma unroll
    for (int qt = 0; qt < 2; qt++)
      lacc[qt] += ldump[qq * 128 + qt * 64 + lane];
    // epilogue: ctx[b][s][h*64+d] bf16; lacc rows coincide with o rows
#pragma unroll
    for (int qt = 0; qt < 2; qt++)
#pragma unroll
      for (int r = 0; r < 4; r++) {
        float inv = 1.0f / lacc[qt][r];
        int s = qbase + qt * 16 + quad * 4 + r;
#pragma unroll
        for (int j = 0; j < 4; j++) {
          int c = h * 64 + j * 16 + (lane & 15);
          ctx[(size_t)(b * 2048 + s) * 1024 + c] = f2bf(o[qt][j][r] * inv);
        }
      }
  }
}

// ---- launch --------------------------------------------------------------
// ws layout (u16 elements, MM = 1024*1024):
//   [0,3MM)    WqT,WkT,WvT bf16        [3MM,4MM)  WoT bf16
//   [4MM,8MM)  x converted to bf16     [8MM,20MM) Q,K row-major (V slot unused)
//   [20MM,24MM) V^T bf16               [24MM,28MM) ctx bf16

extern "C" void kernel_launch(void* const* d_in, const int* in_sizes, int n_in,
                              void* d_out, int out_size, void* d_ws, size_t ws_size,
                              hipStream_t stream) {
  (void)in_sizes; (void)n_in; (void)out_size; (void)ws_size;
  const float* x  = (const float*)d_in[0];
  const float* Wq = (const float*)d_in[1];
  const float* Wk = (const float*)d_in[2];
  const float* Wv = (const float*)d_in[3];
  const float* Wo = (const float*)d_in[4];
  const float* bo = (const float*)d_in[5];
  u16* ws = (u16*)d_ws;
  const size_t MM = 1024 * 1024;
  u16* WT  = ws;             // 3 x [1024][1024] (Wq,Wk,Wv transposed)
  u16* WoT = ws + 3 * MM;    // [1024][1024]
  u16* Xb  = ws + 4 * MM;    // [4096][1024]
  u16* QKV = ws + 8 * MM;    // Q,K row-major [4096][1024] each
  u16* VTp = ws + 20 * MM;   // [32][64][2048]
  u16* CTX = ws + 24 * MM;   // [4096][1024]

  dim3 blk(256);
  prep_kernel<<<dim3(16, 16, 5), blk, 0, stream>>>(Wq, Wk, Wv, Wo, WT, x, Xb);
  gemm_qkv_kernel<<<dim3(8, 32, 3), blk, 0, stream>>>(Xb, WT, QKV, VTp);
  attn_kernel<<<dim3(512, 1, 1), dim3(512), 0, stream>>>(QKV, QKV + 4 * MM, VTp, CTX);
  gemm_o_kernel<<<dim3(16, 64, 1), blk, 0, stream>>>(CTX, WoT, bo, (float*)d_out);
}

// Round 11
// 176.900 us; speedup vs baseline: 1.0218x; 1.0218x over previous
//
#include <hip/hip_runtime.h>
#include <cstdint>

typedef unsigned short u16;
typedef __bf16 bf16x8 __attribute__((ext_vector_type(8)));
typedef __bf16 bf16x2 __attribute__((ext_vector_type(2)));
typedef float floatx4 __attribute__((ext_vector_type(4)));
typedef unsigned short u16x4 __attribute__((ext_vector_type(4)));
typedef unsigned short u16x8 __attribute__((ext_vector_type(8)));

#define MFMA16(a, b, c) __builtin_amdgcn_mfma_f32_16x16x32_bf16((a), (b), (c), 0, 0, 0)
// 0.125 * log2(e): folded into Q so softmax is exp2(st) with no per-elem mul.
#define QSCALE_LOG2E 0.18033688011112042f

// ---- helpers -------------------------------------------------------------

typedef __attribute__((address_space(3))) void as3_void;
typedef __attribute__((address_space(1))) void as1_void;

static __device__ __forceinline__ void async_load16(const void* g, void* l) {
  __builtin_amdgcn_global_load_lds((as1_void*)(uintptr_t)g, (as3_void*)(uintptr_t)l,
                                   16, 0, 0);
}

static __device__ __forceinline__ u16 f2bf(float f) {
  union { float f; unsigned int u; } v; v.f = f;
  unsigned int u = v.u;
  u += 0x7fffu + ((u >> 16) & 1u);   // RNE
  return (u16)(u >> 16);
}

static __device__ __forceinline__ u16x4 pack_bf4(float a, float b, float c, float d) {
#if __has_builtin(__builtin_amdgcn_cvt_pk_bf16_f32)
  union { u16x4 v4; bf16x2 v2[2]; } u;
  u.v2[0] = __builtin_amdgcn_cvt_pk_bf16_f32(a, b);
  u.v2[1] = __builtin_amdgcn_cvt_pk_bf16_f32(c, d);
  return u.v4;
#else
  u16x4 r; r[0] = f2bf(a); r[1] = f2bf(b); r[2] = f2bf(c); r[3] = f2bf(d);
  return r;
#endif
}

static __device__ __forceinline__ unsigned pack_bf2(float a, float b) {
#if __has_builtin(__builtin_amdgcn_cvt_pk_bf16_f32)
  union { bf16x2 v; unsigned u; } x;
  x.v = __builtin_amdgcn_cvt_pk_bf16_f32(a, b);
  return x.u;
#else
  return (unsigned)f2bf(a) | ((unsigned)f2bf(b) << 16);
#endif
}

static __device__ __forceinline__ float fast_exp2(float x) {
#if __has_builtin(__builtin_amdgcn_exp2f)
  return __builtin_amdgcn_exp2f(x);
#else
  return exp2f(x);
#endif
}

// ---- fused: 4x weight transpose+convert (z=0..3) + x convert (z=4) -------

__global__ __launch_bounds__(256) void prep_kernel(
    const float* __restrict__ w0, const float* __restrict__ w1,
    const float* __restrict__ w2, const float* __restrict__ w3,
    u16* __restrict__ wout,
    const float* __restrict__ xin, u16* __restrict__ xout) {
  if (blockIdx.z == 4) {
    int blk = blockIdx.y * 16 + blockIdx.x;
    size_t base = (size_t)blk * 16384 + (size_t)threadIdx.x * 8;
#pragma unroll
    for (int r = 0; r < 8; r++) {
      size_t i = base + (size_t)r * 2048;
      float4 a = *(const float4*)(xin + i);
      float4 b = *(const float4*)(xin + i + 4);
      u16x8 o;
      o[0] = f2bf(a.x); o[1] = f2bf(a.y); o[2] = f2bf(a.z); o[3] = f2bf(a.w);
      o[4] = f2bf(b.x); o[5] = f2bf(b.y); o[6] = f2bf(b.z); o[7] = f2bf(b.w);
      *(u16x8*)(xout + i) = o;
    }
    return;
  }
  __shared__ u16 t[64][65];
  const float* in = (blockIdx.z == 0) ? w0 : (blockIdx.z == 1) ? w1
                    : (blockIdx.z == 2) ? w2 : w3;
  u16* oz = wout + (size_t)blockIdx.z * (1024 * 1024);
  const int tid = threadIdx.x;
  const int x = tid & 63, y0 = tid >> 6;
  const int bx = blockIdx.x * 64, by = blockIdx.y * 64;
#pragma unroll
  for (int p = 0; p < 16; p++) {
    int y = y0 + p * 4;
    t[y][x] = f2bf(in[(size_t)(by + y) * 1024 + bx + x]);
  }
  __syncthreads();
#pragma unroll
  for (int p = 0; p < 16; p++) {
    int r = y0 + p * 4;
    oz[(size_t)(bx + r) * 1024 + by + x] = t[x][r];
  }
}

// ---- QKV GEMM: C[4096][1024] = X @ Wz, Wz given transposed [N][K] --------
// 128x128 tile, BK=32, 4 waves, global_load_lds staging, XOR-swizzled octets.
// Double-buffered As/Bs + raw-barrier loop (R12).
// R15: tb (V^T epilogue staging) ALIASES the As/Bs arena (dead after the
// K-loop: last ds_reads drained by lgkmcnt(0)+barrier, and the epilogue
// opens with __syncthreads).  LDS/block 49 KB -> 32 KB, so the runtime
// occupancy limit moves from 3 blocks/CU (LDS) to 4-5 (registers) with
// launch_bounds unchanged — zero spill risk, +33% TLP.
// z==0 (Q): pre-scaled by QSCALE_LOG2E.  z==1 (K).  z==2 (V): V^T epilogue.

__global__ __launch_bounds__(256, 3) void gemm_qkv_kernel(
    const u16* __restrict__ A, const u16* __restrict__ BT,
    u16* __restrict__ out, u16* __restrict__ outVT) {
  __shared__ __align__(16) u16 sm[2 * 4096 + 2 * 4096];   // 32 KB arena
  u16* As = sm;                      // 2 x 8 KB
  u16* Bs = sm + 2 * 4096;           // 2 x 8 KB
  u16* tb = sm;                      // 64*136 u16 = 17 KB, aliases As+Bs[0..]
  const int tid = threadIdx.x;
  const int w = tid >> 6, lane = tid & 63;
  const int bm = blockIdx.y * 128, bn = blockIdx.x * 128;
  const int z = blockIdx.z;
  const int K = 1024, N = 1024;
  const u16* Bz = BT + (size_t)z * N * K;

  const int c0 = w * 2, c1 = c0 + 1;
  const int mA0 = c0 * 16 + (lane >> 2), mA1 = c1 * 16 + (lane >> 2);
  const int kg0 = (lane & 3) ^ ((mA0 >> 1) & 3);
  const int kg1 = (lane & 3) ^ ((mA1 >> 1) & 3);
  const u16* agp0 = A + (size_t)(bm + mA0) * K + kg0 * 8;
  const u16* agp1 = A + (size_t)(bm + mA1) * K + kg1 * 8;
  const u16* bgp0 = Bz + (size_t)(bn + mA0) * K + kg0 * 8;
  const u16* bgp1 = Bz + (size_t)(bn + mA1) * K + kg1 * 8;

  const int wm = (w >> 1) * 64, wn = (w & 1) * 64;
  floatx4 acc[4][4] = {};

  int a_off[4], b_off[4];
#pragma unroll
  for (int i = 0; i < 4; i++) {
    int m = wm + i * 16 + (lane & 15);
    a_off[i] = m * 32 + (((lane >> 4) ^ ((m >> 1) & 3)) * 8);
    int n = wn + i * 16 + (lane & 15);
    b_off[i] = n * 32 + (((lane >> 4) ^ ((n >> 1) & 3)) * 8);
  }

  auto issueQ = [&](int buf, int k0) {
    u16* ab = As + buf * 4096;
    u16* bb = Bs + buf * 4096;
    async_load16(agp0 + k0, ab + c0 * 512);
    async_load16(agp1 + k0, ab + c1 * 512);
    async_load16(bgp0 + k0, bb + c0 * 512);
    async_load16(bgp1 + k0, bb + c1 * 512);
  };

  issueQ(0, 0);
  asm volatile("s_waitcnt vmcnt(0)" ::: "memory");
  __builtin_amdgcn_s_barrier();

#pragma unroll 2
  for (int kk = 0; kk < 32; ++kk) {
    if (kk < 31) issueQ((kk + 1) & 1, (kk + 1) * 32);
    const u16* Ab = As + (kk & 1) * 4096;
    const u16* Bb = Bs + (kk & 1) * 4096;
    bf16x8 af[4], bf[4];
#pragma unroll
    for (int i = 0; i < 4; i++) af[i] = *(const bf16x8*)(Ab + a_off[i]);
#pragma unroll
    for (int j = 0; j < 4; j++) bf[j] = *(const bf16x8*)(Bb + b_off[j]);
    __builtin_amdgcn_s_setprio(1);
#pragma unroll
    for (int i = 0; i < 4; i++)
#pragma unroll
      for (int j = 0; j < 4; j++)
        acc[i][j] = MFMA16(af[i], bf[j], acc[i][j]);
    __builtin_amdgcn_s_setprio(0);
    // own loads for kk+1 landed + own reads of this buf done, then converge
    asm volatile("s_waitcnt vmcnt(0) lgkmcnt(0)" ::: "memory");
    __builtin_amdgcn_s_barrier();
  }

  // epilogue: C/D layout col=lane&15, row=(lane>>4)*4+reg  [m89]
  const int roff = (lane >> 4) * 4;
  const int coff = lane & 15;
  if (z == 2) {
    // V^T: two 64-col halves through padded LDS, then coalesced b128 stores
    const int b = bm >> 11, s0 = bm & 2047;
#pragma unroll
    for (int half = 0; half < 2; half++) {
      __syncthreads();
      if ((w & 1) == half) {
#pragma unroll
        for (int i = 0; i < 4; i++) {
          int s_local = wm + i * 16 + roff;
#pragma unroll
          for (int j = 0; j < 4; j++) {
            int c_local = j * 16 + coff;     // 0..63 within half
            u16x4 pk = pack_bf4(acc[i][j][0], acc[i][j][1],
                                acc[i][j][2], acc[i][j][3]);
            *(u16x4*)(tb + c_local * 136 + s_local) = pk;
          }
        }
      }
      __syncthreads();
      // store: 16 consecutive lanes cover one d-row's 128 s (256B contiguous)
#pragma unroll
      for (int p = 0; p < 4; p++) {
        int c_local = (tid >> 4) & 15;       // 0..15
        int row = p * 16 + c_local;          // 0..63
        int so = tid & 15;
        int cg = bn + half * 64 + row;
        int h = cg >> 6, d = cg & 63;
        u16x8 vv = *(const u16x8*)(tb + row * 136 + so * 8);
        *(u16x8*)(outVT + ((size_t)(b * 16 + h) * 64 + d) * 2048 + s0 + so * 8) = vv;
      }
    }
  } else {
    const float sc = (z == 0) ? QSCALE_LOG2E : 1.0f;
    u16* outz = out + (size_t)z * 4096 * 1024;
#pragma unroll
    for (int i = 0; i < 4; i++) {
      int r0 = bm + wm + i * 16 + roff;
#pragma unroll
      for (int j = 0; j < 4; j++) {
        int c = bn + wn + j * 16 + coff;
#pragma unroll
        for (int r = 0; r < 4; r++)
          outz[(size_t)(r0 + r) * N + c] = f2bf(acc[i][j][r] * sc);
      }
    }
  }
}

// ---- O GEMM: out[4096][1024] f32 = CTX @ Wo + bo -------------------------
// 128m x 64n tile, BK=32, 4 waves (2x2 of 64x32) -> 512 blocks = 2/CU.
// Double-buffer + raw-barrier structure (R12).

__global__ __launch_bounds__(256, 2) void gemm_o_kernel(
    const u16* __restrict__ A, const u16* __restrict__ BT,
    const float* __restrict__ bias, float* __restrict__ out) {
  __shared__ u16 As[2 * 4096];
  __shared__ u16 Bs[2 * 2048];
  const int tid = threadIdx.x;
  const int w = tid >> 6, lane = tid & 63;
  const int bm = blockIdx.y * 128, bn = blockIdx.x * 64;
  const int K = 1024, N = 1024;

  const u16* gp[3];
  u16* ldp[2][3];
#pragma unroll
  for (int i = 0; i < 3; i++) {
    int c = w * 3 + i;
    if (c < 8) {
      int m = c * 16 + (lane >> 2);
      int kg = (lane & 3) ^ ((m >> 1) & 3);
      gp[i] = A + (size_t)(bm + m) * K + kg * 8;
      ldp[0][i] = As + c * 512;
      ldp[1][i] = As + 4096 + c * 512;
    } else {
      int cb = c - 8;
      int n = cb * 16 + (lane >> 2);
      int kg = (lane & 3) ^ ((n >> 1) & 3);
      gp[i] = BT + (size_t)(bn + n) * K + kg * 8;
      ldp[0][i] = Bs + cb * 512;
      ldp[1][i] = Bs + 2048 + cb * 512;
    }
  }

  const int wm = (w >> 1) * 64, wn = (w & 1) * 32;
  floatx4 acc[4][2] = {};

  int a_off[4], b_off[2];
#pragma unroll
  for (int i = 0; i < 4; i++) {
    int m = wm + i * 16 + (lane & 15);
    a_off[i] = m * 32 + (((lane >> 4) ^ ((m >> 1) & 3)) * 8);
  }
#pragma unroll
  for (int j = 0; j < 2; j++) {
    int n = wn + j * 16 + (lane & 15);
    b_off[j] = n * 32 + (((lane >> 4) ^ ((n >> 1) & 3)) * 8);
  }

  auto issueO = [&](int buf, int k0) {
#pragma unroll
    for (int i = 0; i < 3; i++)
      async_load16(gp[i] + k0, buf ? ldp[1][i] : ldp[0][i]);
  };

  issueO(0, 0);
  asm volatile("s_waitcnt vmcnt(0)" ::: "memory");
  __builtin_amdgcn_s_barrier();

#pragma unroll 2
  for (int kk = 0; kk < 32; ++kk) {
    if (kk < 31) issueO((kk + 1) & 1, (kk + 1) * 32);
    const u16* Ab = As + (kk & 1) * 4096;
    const u16* Bb = Bs + (kk & 1) * 2048;
    bf16x8 af[4], bf[2];
#pragma unroll
    for (int i = 0; i < 4; i++) af[i] = *(const bf16x8*)(Ab + a_off[i]);
#pragma unroll
    for (int j = 0; j < 2; j++) bf[j] = *(const bf16x8*)(Bb + b_off[j]);
    __builtin_amdgcn_s_setprio(1);
#pragma unroll
    for (int i = 0; i < 4; i++)
#pragma unroll
      for (int j = 0; j < 2; j++)
        acc[i][j] = MFMA16(af[i], bf[j], acc[i][j]);
    __builtin_amdgcn_s_setprio(0);
    asm volatile("s_waitcnt vmcnt(0) lgkmcnt(0)" ::: "memory");
    __builtin_amdgcn_s_barrier();
  }

  const int roff = (lane >> 4) * 4;
  const int coff = lane & 15;
#pragma unroll
  for (int i = 0; i < 4; i++) {
    int r0 = bm + wm + i * 16 + roff;
#pragma unroll
    for (int j = 0; j < 2; j++) {
      int c = bn + wn + j * 16 + coff;
      float bv = bias[c];
#pragma unroll
      for (int r = 0; r < 4; r++)
        out[(size_t)(r0 + r) * N + c] = acc[i][j][r] + bv;
    }
  }
}

// ---- flash attention (no-max softmax, 512-thread blocks, s-split pairs) --
// Q (pre-scaled), K: [b*2048+s][1024] row-major bf16, head at col h*64.
// VT: [bh][64][2048] bf16.  ctx: [b][s][1024] bf16.
// Block = 8 waves over a 128q x 128s tile: wave (qq,sh) = q-quarter qq
// (32 rows in registers as B-operand) x s-half sh (64 cols).
//
// Verified at 50.6-51.5 us.  R12/R13/R14 pipeline-deepening all spilled:
// per-wave state ~120 regs on the UNIFIED gfx950 VGPR/AGPR file caps
// occupancy at 4 waves/SIMD; do not add live state across the QK phase.
// In-register P (permlane16_swap, sigma=(0,2,1,3) absorbed into vf slot);
// K/V double-buffered, one raw barrier + one vmcnt(0) per iteration.

__global__ __launch_bounds__(512, 4) void attn_kernel(
    const u16* __restrict__ Q, const u16* __restrict__ Kx,
    const u16* __restrict__ VT, u16* __restrict__ ctx) {
  // arena: 2 x { Ks [128s][64d] | Vs [64d][128s] } = 64 KB
  __shared__ __align__(16) u16 lds[32768];
  const int tid = threadIdx.x;
  const int w = tid >> 6, lane = tid & 63;
  const int qq = w >> 1, sh = w & 1;
  const int quad = lane >> 4;
  const int bid = blockIdx.x;
  const int bh = (bid >> 7) * 8 + (bid & 7);      // XCD-pinned head group
  const int q0 = ((bid >> 3) & 15) * 128;
  const int b = bh >> 4, h = bh & 15;
  const u16* Qh = Q + (size_t)b * 2048 * 1024 + h * 64;
  const u16* Kh = Kx + (size_t)b * 2048 * 1024 + h * 64;
  const u16* Vh = VT + (size_t)bh * 64 * 2048;

  // staging: wave w owns Ks chunks {2w,2w+1} and Vs chunks {2w,2w+1}
  const u16* kgp[2]; const u16* vgp[2];
  int kc[2], vc[2];
#pragma unroll
  for (int i = 0; i < 2; i++) {
    int c = w * 2 + i;                 // 0..15
    int sl = c * 8 + (lane >> 3);
    int dg = (lane & 7) ^ (lane >> 3);
    kgp[i] = Kh + (size_t)sl * 1024 + dg * 8;
    kc[i] = c * 512;
    int dl = c * 4 + quad;
    int sg = (lane & 15) ^ (dl & 15);
    vgp[i] = Vh + (size_t)dl * 2048 + sg * 8;
    vc[i] = 8192 + c * 512;
  }

  auto issue_tile = [&](int buf, int t) {
    u16* dst = lds + buf * 16384;
    const size_t k0 = (size_t)t * 128;
#pragma unroll
    for (int i = 0; i < 2; i++) {
      async_load16(kgp[i] + k0 * 1024, dst + kc[i]);
      async_load16(vgp[i] + k0, dst + vc[i]);
    }
  };

  issue_tile(0, 0);                    // tile 0 loads overlap Q-frag loads

  // Q fragments: 32 q-rows/wave (B-operand: col=lane&15, k-octet=quad)
  const int qbase = q0 + qq * 32;
  bf16x8 qf[2][2];
#pragma unroll
  for (int qt = 0; qt < 2; qt++)
#pragma unroll
    for (int ks = 0; ks < 2; ks++)
      qf[qt][ks] = *(const bf16x8*)(Qh + (size_t)(qbase + qt * 16 + (lane & 15)) * 1024 +
                                    ks * 32 + quad * 8);

  bf16x8 onesf;
#pragma unroll
  for (int i = 0; i < 8; i++) onesf[i] = (__bf16)1.0f;
  const floatx4 zero4 = {};

  // K-fragment LDS offsets for this wave's s-half (4 slabs of 16 s)
  const int slot_k0 = quad ^ (lane & 7);
  const int slot_k1 = (4 + quad) ^ (lane & 7);
  const int koff0 = sh * 4096 + (lane & 15) * 64 + slot_k0 * 8;
  const int koff1 = sh * 4096 + (lane & 15) * 64 + slot_k1 * 8;
  // V-fragment offsets: MFMA k-octet Q holds s-octet sigma(Q)=bitrev2(Q)
  const int sq = ((quad & 1) << 1) | (quad >> 1);

  floatx4 o[2][4] = {};
  floatx4 lacc[2] = {};              // partial row sums (this s-half)

  // drain qf + tile-0 staging once so the loop's vmcnt discipline is clean
  asm volatile("s_waitcnt vmcnt(0)" ::: "memory");

#pragma unroll 2
  for (int t = 0; t < 16; ++t) {
    __builtin_amdgcn_s_barrier();        // tile t visible to all waves
    __builtin_amdgcn_sched_barrier(0);
    if (t < 15) issue_tile((t + 1) & 1, t + 1);   // in flight across compute
    const u16* Ksb = lds + (t & 1) * 16384;
    const u16* Vsb = Ksb + 8192;

    // QK for this wave's 4 slabs (batched: 16 MFMAs in flight)
    floatx4 st[4][2];
    __builtin_amdgcn_s_setprio(1);
#pragma unroll
    for (int si = 0; si < 4; si++) {
      bf16x8 kf0 = *(const bf16x8*)(Ksb + koff0 + si * 1024);
      bf16x8 kf1 = *(const bf16x8*)(Ksb + koff1 + si * 1024);
#pragma unroll
      for (int qt = 0; qt < 2; qt++)
        st[si][qt] = MFMA16(kf1, qf[qt][1], MFMA16(kf0, qf[qt][0], zero4));
    }
    __builtin_amdgcn_s_setprio(0);

    // p = exp2(st), pack to bf16 pairs: pa = regs{0,1}, pb = regs{2,3}
    unsigned pa[2][4], pb[2][4];
#pragma unroll
    for (int si = 0; si < 4; si++)
#pragma unroll
      for (int qt = 0; qt < 2; qt++) {
        pa[qt][si] = pack_bf2(fast_exp2(st[si][qt][0]), fast_exp2(st[si][qt][1]));
        pb[qt][si] = pack_bf2(fast_exp2(st[si][qt][2]), fast_exp2(st[si][qt][3]));
      }

    // in-register P->A-operand: swap quad pairs; resulting k-octet order is
    // sigma = (0,2,1,3), matched by the vf slot below.
    bf16x8 pf[2][2];
#pragma unroll
    for (int qt = 0; qt < 2; qt++)
#pragma unroll
      for (int ksl = 0; ksl < 2; ksl++) {
        unsigned x0 = pa[qt][2 * ksl], x1 = pa[qt][2 * ksl + 1];
        unsigned y0 = pb[qt][2 * ksl], y1 = pb[qt][2 * ksl + 1];
        asm("v_permlane16_swap_b32 %0, %1" : "+v"(x0), "+v"(x1));
        asm("v_permlane16_swap_b32 %0, %1" : "+v"(y0), "+v"(y1));
        union { unsigned u[4]; bf16x8 v; } uu;
        uu.u[0] = x0; uu.u[1] = y0; uu.u[2] = x1; uu.u[3] = y1;
        pf[qt][ksl] = uu.v;
      }

    // O += P . V over this s-half's two 32-s blocks
    __builtin_amdgcn_s_setprio(1);
#pragma unroll
    for (int ksl = 0; ksl < 2; ksl++) {
      int kb = sh * 2 + ksl;
      bf16x8 vf[4];
#pragma unroll
      for (int jt = 0; jt < 4; jt++) {
        int d = jt * 16 + (lane & 15);
        int slot = (kb * 4 + sq) ^ (d & 15);
        vf[jt] = *(const bf16x8*)(Vsb + d * 128 + slot * 8);
      }
#pragma unroll
      for (int qt = 0; qt < 2; qt++) {
#pragma unroll
        for (int jt = 0; jt < 4; jt++)
          o[qt][jt] = MFMA16(pf[qt][ksl], vf[jt], o[qt][jt]);
        lacc[qt] = MFMA16(pf[qt][ksl], onesf, lacc[qt]);
      }
    }
    __builtin_amdgcn_s_setprio(0);
    // own tile-(t+1) loads must be done before the next barrier
    asm volatile("s_waitcnt vmcnt(0)" ::: "memory");
  }

  // combine s-halves: sh==1 dumps O,l; sh==0 adds + stores.
  // dump region = lds[0..32KB) for O (2048 floatx4), [32KB..40KB) for l.
  __syncthreads();
  floatx4* dump  = (floatx4*)lds;
  floatx4* ldump = (floatx4*)(lds + 16384);
  if (sh == 1) {
    int base = qq * 512;
#pragma unroll
    for (int qt = 0; qt < 2; qt++)
#pragma unroll
      for (int jt = 0; jt < 4; jt++)
        dump[base + (qt * 4 + jt) * 64 + lane] = o[qt][jt];
#pragma unroll
    for (int qt = 0; qt < 2; qt++)
      ldump[qq * 128 + qt * 64 + lane] = lacc[qt];
  }
  __syncthreads();
  if (sh == 0) {
    int base = qq * 512;
#pragma unroll
    for (int qt = 0; qt < 2; qt++)
#pragma unroll
      for (int jt = 0; jt < 4; jt++)
        o[qt][jt] += dump[base + (qt * 4 + jt) * 64 + lane];
#pragma unroll
    for (int qt = 0; qt < 2; qt++)
      lacc[qt] += ldump[qq * 128 + qt * 64 + lane];
    // epilogue: ctx[b][s][h*64+d] bf16; lacc rows coincide with o rows
#pragma unroll
    for (int qt = 0; qt < 2; qt++)
#pragma unroll
      for (int r = 0; r < 4; r++) {
        float inv = 1.0f / lacc[qt][r];
        int s = qbase + qt * 16 + quad * 4 + r;
#pragma unroll
        for (int j = 0; j < 4; j++) {
          int c = h * 64 + j * 16 + (lane & 15);
          ctx[(size_t)(b * 2048 + s) * 1024 + c] = f2bf(o[qt][j][r] * inv);
        }
      }
  }
}

// ---- launch --------------------------------------------------------------
// ws layout (u16 elements, MM = 1024*1024):
//   [0,3MM)    WqT,WkT,WvT bf16        [3MM,4MM)  WoT bf16
//   [4MM,8MM)  x converted to bf16     [8MM,20MM) Q,K row-major (V slot unused)
//   [20MM,24MM) V^T bf16               [24MM,28MM) ctx bf16

extern "C" void kernel_launch(void* const* d_in, const int* in_sizes, int n_in,
                              void* d_out, int out_size, void* d_ws, size_t ws_size,
                              hipStream_t stream) {
  (void)in_sizes; (void)n_in; (void)out_size; (void)ws_size;
  const float* x  = (const float*)d_in[0];
  const float* Wq = (const float*)d_in[1];
  const float* Wk = (const float*)d_in[2];
  const float* Wv = (const float*)d_in[3];
  const float* Wo = (const float*)d_in[4];
  const float* bo = (const float*)d_in[5];
  u16* ws = (u16*)d_ws;
  const size_t MM = 1024 * 1024;
  u16* WT  = ws;             // 3 x [1024][1024] (Wq,Wk,Wv transposed)
  u16* WoT = ws + 3 * MM;    // [1024][1024]
  u16* Xb  = ws + 4 * MM;    // [4096][1024]
  u16* QKV = ws + 8 * MM;    // Q,K row-major [4096][1024] each
  u16* VTp = ws + 20 * MM;   // [32][64][2048]
  u16* CTX = ws + 24 * MM;   // [4096][1024]

  dim3 blk(256);
  prep_kernel<<<dim3(16, 16, 5), blk, 0, stream>>>(Wq, Wk, Wv, Wo, WT, x, Xb);
  gemm_qkv_kernel<<<dim3(8, 32, 3), blk, 0, stream>>>(Xb, WT, QKV, VTp);
  attn_kernel<<<dim3(512, 1, 1), dim3(512), 0, stream>>>(QKV, QKV + 4 * MM, VTp, CTX);
  gemm_o_kernel<<<dim3(16, 32, 1), blk, 0, stream>>>(CTX, WoT, bo, (float*)d_out);
}

// Round 12
// 176.127 us; speedup vs baseline: 1.0263x; 1.0044x over previous
//
#include <hip/hip_runtime.h>
#include <cstdint>

typedef unsigned short u16;
typedef __bf16 bf16x8 __attribute__((ext_vector_type(8)));
typedef __bf16 bf16x2 __attribute__((ext_vector_type(2)));
typedef float floatx4 __attribute__((ext_vector_type(4)));
typedef unsigned short u16x4 __attribute__((ext_vector_type(4)));
typedef unsigned short u16x8 __attribute__((ext_vector_type(8)));

#define MFMA16(a, b, c) __builtin_amdgcn_mfma_f32_16x16x32_bf16((a), (b), (c), 0, 0, 0)
// 0.125 * log2(e): folded into Q so softmax is exp2(st) with no per-elem mul.
#define QSCALE_LOG2E 0.18033688011112042f

// ---- helpers -------------------------------------------------------------

typedef __attribute__((address_space(3))) void as3_void;
typedef __attribute__((address_space(1))) void as1_void;

static __device__ __forceinline__ void async_load16(const void* g, void* l) {
  __builtin_amdgcn_global_load_lds((as1_void*)(uintptr_t)g, (as3_void*)(uintptr_t)l,
                                   16, 0, 0);
}

static __device__ __forceinline__ u16 f2bf(float f) {
  union { float f; unsigned int u; } v; v.f = f;
  unsigned int u = v.u;
  u += 0x7fffu + ((u >> 16) & 1u);   // RNE
  return (u16)(u >> 16);
}

static __device__ __forceinline__ u16x4 pack_bf4(float a, float b, float c, float d) {
#if __has_builtin(__builtin_amdgcn_cvt_pk_bf16_f32)
  union { u16x4 v4; bf16x2 v2[2]; } u;
  u.v2[0] = __builtin_amdgcn_cvt_pk_bf16_f32(a, b);
  u.v2[1] = __builtin_amdgcn_cvt_pk_bf16_f32(c, d);
  return u.v4;
#else
  u16x4 r; r[0] = f2bf(a); r[1] = f2bf(b); r[2] = f2bf(c); r[3] = f2bf(d);
  return r;
#endif
}

static __device__ __forceinline__ unsigned pack_bf2(float a, float b) {
#if __has_builtin(__builtin_amdgcn_cvt_pk_bf16_f32)
  union { bf16x2 v; unsigned u; } x;
  x.v = __builtin_amdgcn_cvt_pk_bf16_f32(a, b);
  return x.u;
#else
  return (unsigned)f2bf(a) | ((unsigned)f2bf(b) << 16);
#endif
}

static __device__ __forceinline__ float fast_exp2(float x) {
#if __has_builtin(__builtin_amdgcn_exp2f)
  return __builtin_amdgcn_exp2f(x);
#else
  return exp2f(x);
#endif
}

// ---- fused: 4x weight transpose+convert (z=0..3) + x convert (z=4) -------

__global__ __launch_bounds__(256) void prep_kernel(
    const float* __restrict__ w0, const float* __restrict__ w1,
    const float* __restrict__ w2, const float* __restrict__ w3,
    u16* __restrict__ wout,
    const float* __restrict__ xin, u16* __restrict__ xout) {
  if (blockIdx.z == 4) {
    int blk = blockIdx.y * 16 + blockIdx.x;
    size_t base = (size_t)blk * 16384 + (size_t)threadIdx.x * 8;
#pragma unroll
    for (int r = 0; r < 8; r++) {
      size_t i = base + (size_t)r * 2048;
      float4 a = *(const float4*)(xin + i);
      float4 b = *(const float4*)(xin + i + 4);
      u16x8 o;
      o[0] = f2bf(a.x); o[1] = f2bf(a.y); o[2] = f2bf(a.z); o[3] = f2bf(a.w);
      o[4] = f2bf(b.x); o[5] = f2bf(b.y); o[6] = f2bf(b.z); o[7] = f2bf(b.w);
      *(u16x8*)(xout + i) = o;
    }
    return;
  }
  __shared__ u16 t[64][65];
  const float* in = (blockIdx.z == 0) ? w0 : (blockIdx.z == 1) ? w1
                    : (blockIdx.z == 2) ? w2 : w3;
  u16* oz = wout + (size_t)blockIdx.z * (1024 * 1024);
  const int tid = threadIdx.x;
  const int x = tid & 63, y0 = tid >> 6;
  const int bx = blockIdx.x * 64, by = blockIdx.y * 64;
#pragma unroll
  for (int p = 0; p < 16; p++) {
    int y = y0 + p * 4;
    t[y][x] = f2bf(in[(size_t)(by + y) * 1024 + bx + x]);
  }
  __syncthreads();
#pragma unroll
  for (int p = 0; p < 16; p++) {
    int r = y0 + p * 4;
    oz[(size_t)(bx + r) * 1024 + by + x] = t[x][r];
  }
}

// ---- fused QKV GEMM: Q,K,V tiles for one (bm,bn) in ONE block ------------
// R18 (= R17 de-aliased): tile 128m x 64n, all 3 weights per block.  A-tile
// (Xb) staged ONCE per K-step feeds 3 GEMMs (24 MFMA/wave per 20 loads vs 16
// per 12 over 3 blocks; A HBM/L2 traffic / 3).  Grid 768 -> 512 blocks.
// acc[3][4][2] = 96 VGPR, total ~160 < 256 cap of __launch_bounds__(256,2);
// all acc indexing compile-time.  LDS: 40 KB dbuf arena + DEDICATED 9 KB tb2
// (R17's tb aliased the live dbuf arena — the one unproven element of the 4x
// container-failed round; de-aliasing costs nothing: 49 KB still 3 blocks/CU
// since regs limit at 3 anyway).  V^T epilogue in two 64-s passes.

__global__ __launch_bounds__(256, 2) void gemm_qkv_kernel(
    const u16* __restrict__ A, const u16* __restrict__ BT,
    u16* __restrict__ out, u16* __restrict__ outVT) {
  __shared__ __align__(16) u16 sm[2 * 10240];   // 2 x (A 4096 + B 3*2048)
  __shared__ __align__(16) u16 tb2[64 * 72];    // V^T staging, one 64-s half
  const int tid = threadIdx.x;
  const int w = tid >> 6, lane = tid & 63;
  const int bm = blockIdx.y * 128, bn = blockIdx.x * 64;
  const int K = 1024, N = 1024;

  // staging: 20 chunks of 512 u16 (0..7 = A 16-row slabs, 8..19 = B z*4+cb);
  // wave w owns chunks 5w..5w+4.  Global src pre-swizzled to fragment slots.
  const u16* gp[5];
  int lo[5];
#pragma unroll
  for (int i = 0; i < 5; i++) {
    int c = w * 5 + i;
    if (c < 8) {
      int m = c * 16 + (lane >> 2);
      int kg = (lane & 3) ^ ((m >> 1) & 3);
      gp[i] = A + (size_t)(bm + m) * K + kg * 8;
      lo[i] = c * 512;
    } else {
      int cz = c - 8;                    // 0..11: z = cz>>2, cb = cz&3
      int z = cz >> 2;
      int n = (cz & 3) * 16 + (lane >> 2);
      int kg = (lane & 3) ^ ((n >> 1) & 3);
      gp[i] = BT + (size_t)z * N * K + (size_t)(bn + n) * K + kg * 8;
      lo[i] = 4096 + cz * 512;
    }
  }

  const int wm = (w >> 1) * 64, wn = (w & 1) * 32;
  floatx4 acc[3][4][2] = {};

  int a_off[4], b_off[2];
#pragma unroll
  for (int i = 0; i < 4; i++) {
    int m = wm + i * 16 + (lane & 15);
    a_off[i] = m * 32 + (((lane >> 4) ^ ((m >> 1) & 3)) * 8);
  }
#pragma unroll
  for (int j = 0; j < 2; j++) {
    int n = wn + j * 16 + (lane & 15);
    b_off[j] = n * 32 + (((lane >> 4) ^ ((n >> 1) & 3)) * 8);
  }

  auto issueQ = [&](int buf, int k0) {
    u16* base = sm + buf * 10240;
#pragma unroll
    for (int i = 0; i < 5; i++)
      async_load16(gp[i] + k0, base + lo[i]);
  };

  issueQ(0, 0);
  asm volatile("s_waitcnt vmcnt(0)" ::: "memory");
  __builtin_amdgcn_s_barrier();

#pragma unroll 2
  for (int kk = 0; kk < 32; ++kk) {
    if (kk < 31) issueQ((kk + 1) & 1, (kk + 1) * 32);
    const u16* Ab = sm + (kk & 1) * 10240;
    bf16x8 af[4];
#pragma unroll
    for (int i = 0; i < 4; i++) af[i] = *(const bf16x8*)(Ab + a_off[i]);
    __builtin_amdgcn_s_setprio(1);
#pragma unroll
    for (int z = 0; z < 3; z++) {
      const u16* Bb = Ab + 4096 + z * 2048;
      bf16x8 bf[2];
#pragma unroll
      for (int j = 0; j < 2; j++) bf[j] = *(const bf16x8*)(Bb + b_off[j]);
#pragma unroll
      for (int i = 0; i < 4; i++)
#pragma unroll
        for (int j = 0; j < 2; j++)
          acc[z][i][j] = MFMA16(af[i], bf[j], acc[z][i][j]);
    }
    __builtin_amdgcn_s_setprio(0);
    // own loads for kk+1 landed + own reads of this buf done, then converge
    asm volatile("s_waitcnt vmcnt(0) lgkmcnt(0)" ::: "memory");
    __builtin_amdgcn_s_barrier();
  }

  // epilogue: C/D layout col=lane&15, row=(lane>>4)*4+reg  [m89]
  const int roff = (lane >> 4) * 4;
  const int coff = lane & 15;

  // Q (scaled) and K row-major stores
#pragma unroll
  for (int z = 0; z < 2; z++) {
    const float sc = (z == 0) ? QSCALE_LOG2E : 1.0f;
    u16* outz = out + (size_t)z * 4096 * 1024;
#pragma unroll
    for (int i = 0; i < 4; i++) {
      int r0 = bm + wm + i * 16 + roff;
#pragma unroll
      for (int j = 0; j < 2; j++) {
        int c = bn + wn + j * 16 + coff;
#pragma unroll
        for (int r = 0; r < 4; r++)
          outz[(size_t)(r0 + r) * N + c] = f2bf(acc[z][i][j][r] * sc);
      }
    }
  }

  // V^T in two 64-s passes through the dedicated tb2 buffer.
  // Pass ha: waves with wm==ha*64 stage their 64 s-rows; all waves store.
  const int b = bm >> 11, s0 = bm & 2047;
#pragma unroll
  for (int ha = 0; ha < 2; ha++) {
    __syncthreads();
    if ((w >> 1) == ha) {
#pragma unroll
      for (int i = 0; i < 4; i++) {
        int s_l = i * 16 + roff;               // 0..63 within half
#pragma unroll
        for (int j = 0; j < 2; j++) {
          int c_local = wn + j * 16 + coff;    // 0..63
          u16x4 pk = pack_bf4(acc[2][i][j][0], acc[2][i][j][1],
                              acc[2][i][j][2], acc[2][i][j][3]);
          *(u16x4*)(tb2 + c_local * 72 + s_l) = pk;
        }
      }
    }
    __syncthreads();
    // store: 8 lanes cover one (h,d) row's 64 s (128B contiguous)
#pragma unroll
    for (int p = 0; p < 2; p++) {
      int row = p * 32 + (tid >> 3);           // 0..63
      int so = tid & 7;
      int cg = bn + row;
      int h = cg >> 6, d = cg & 63;
      u16x8 vv = *(const u16x8*)(tb2 + row * 72 + so * 8);
      *(u16x8*)(outVT + ((size_t)(b * 16 + h) * 64 + d) * 2048 +
                s0 + ha * 64 + so * 8) = vv;
    }
  }
}

// ---- O GEMM: out[4096][1024] f32 = CTX @ Wo + bo -------------------------
// 128m x 64n tile, BK=32, 4 waves (2x2 of 64x32) -> 512 blocks = 2/CU.
// Double-buffer + raw-barrier structure (R12).

__global__ __launch_bounds__(256, 2) void gemm_o_kernel(
    const u16* __restrict__ A, const u16* __restrict__ BT,
    const float* __restrict__ bias, float* __restrict__ out) {
  __shared__ u16 As[2 * 4096];
  __shared__ u16 Bs[2 * 2048];
  const int tid = threadIdx.x;
  const int w = tid >> 6, lane = tid & 63;
  const int bm = blockIdx.y * 128, bn = blockIdx.x * 64;
  const int K = 1024, N = 1024;

  const u16* gp[3];
  u16* ldp[2][3];
#pragma unroll
  for (int i = 0; i < 3; i++) {
    int c = w * 3 + i;
    if (c < 8) {
      int m = c * 16 + (lane >> 2);
      int kg = (lane & 3) ^ ((m >> 1) & 3);
      gp[i] = A + (size_t)(bm + m) * K + kg * 8;
      ldp[0][i] = As + c * 512;
      ldp[1][i] = As + 4096 + c * 512;
    } else {
      int cb = c - 8;
      int n = cb * 16 + (lane >> 2);
      int kg = (lane & 3) ^ ((n >> 1) & 3);
      gp[i] = BT + (size_t)(bn + n) * K + kg * 8;
      ldp[0][i] = Bs + cb * 512;
      ldp[1][i] = Bs + 2048 + cb * 512;
    }
  }

  const int wm = (w >> 1) * 64, wn = (w & 1) * 32;
  floatx4 acc[4][2] = {};

  int a_off[4], b_off[2];
#pragma unroll
  for (int i = 0; i < 4; i++) {
    int m = wm + i * 16 + (lane & 15);
    a_off[i] = m * 32 + (((lane >> 4) ^ ((m >> 1) & 3)) * 8);
  }
#pragma unroll
  for (int j = 0; j < 2; j++) {
    int n = wn + j * 16 + (lane & 15);
    b_off[j] = n * 32 + (((lane >> 4) ^ ((n >> 1) & 3)) * 8);
  }

  auto issueO = [&](int buf, int k0) {
#pragma unroll
    for (int i = 0; i < 3; i++)
      async_load16(gp[i] + k0, buf ? ldp[1][i] : ldp[0][i]);
  };

  issueO(0, 0);
  asm volatile("s_waitcnt vmcnt(0)" ::: "memory");
  __builtin_amdgcn_s_barrier();

#pragma unroll 2
  for (int kk = 0; kk < 32; ++kk) {
    if (kk < 31) issueO((kk + 1) & 1, (kk + 1) * 32);
    const u16* Ab = As + (kk & 1) * 4096;
    const u16* Bb = Bs + (kk & 1) * 2048;
    bf16x8 af[4], bf[2];
#pragma unroll
    for (int i = 0; i < 4; i++) af[i] = *(const bf16x8*)(Ab + a_off[i]);
#pragma unroll
    for (int j = 0; j < 2; j++) bf[j] = *(const bf16x8*)(Bb + b_off[j]);
    __builtin_amdgcn_s_setprio(1);
#pragma unroll
    for (int i = 0; i < 4; i++)
#pragma unroll
      for (int j = 0; j < 2; j++)
        acc[i][j] = MFMA16(af[i], bf[j], acc[i][j]);
    __builtin_amdgcn_s_setprio(0);
    asm volatile("s_waitcnt vmcnt(0) lgkmcnt(0)" ::: "memory");
    __builtin_amdgcn_s_barrier();
  }

  const int roff = (lane >> 4) * 4;
  const int coff = lane & 15;
#pragma unroll
  for (int i = 0; i < 4; i++) {
    int r0 = bm + wm + i * 16 + roff;
#pragma unroll
    for (int j = 0; j < 2; j++) {
      int c = bn + wn + j * 16 + coff;
      float bv = bias[c];
#pragma unroll
      for (int r = 0; r < 4; r++)
        out[(size_t)(r0 + r) * N + c] = acc[i][j][r] + bv;
    }
  }
}

// ---- flash attention (no-max softmax, 512-thread blocks, s-split pairs) --
// Q (pre-scaled), K: [b*2048+s][1024] row-major bf16, head at col h*64.
// VT: [bh][64][2048] bf16.  ctx: [b][s][1024] bf16.
// Block = 8 waves over a 128q x 128s tile: wave (qq,sh) = q-quarter qq
// (32 rows in registers as B-operand) x s-half sh (64 cols).
//
// Verified at 50.2-51.5 us.  R12/R13/R14 pipeline-deepening all spilled:
// per-wave state ~120 regs on the UNIFIED gfx950 VGPR/AGPR file caps
// occupancy at 4 waves/SIMD; do not add live state across the QK phase.
// In-register P (permlane16_swap, sigma=(0,2,1,3) absorbed into vf slot);
// K/V double-buffered, one raw barrier + one vmcnt(0) per iteration.

__global__ __launch_bounds__(512, 4) void attn_kernel(
    const u16* __restrict__ Q, const u16* __restrict__ Kx,
    const u16* __restrict__ VT, u16* __restrict__ ctx) {
  // arena: 2 x { Ks [128s][64d] | Vs [64d][128s] } = 64 KB
  __shared__ __align__(16) u16 lds[32768];
  const int tid = threadIdx.x;
  const int w = tid >> 6, lane = tid & 63;
  const int qq = w >> 1, sh = w & 1;
  const int quad = lane >> 4;
  const int bid = blockIdx.x;
  const int bh = (bid >> 7) * 8 + (bid & 7);      // XCD-pinned head group
  const int q0 = ((bid >> 3) & 15) * 128;
  const int b = bh >> 4, h = bh & 15;
  const u16* Qh = Q + (size_t)b * 2048 * 1024 + h * 64;
  const u16* Kh = Kx + (size_t)b * 2048 * 1024 + h * 64;
  const u16* Vh = VT + (size_t)bh * 64 * 2048;

  // staging: wave w owns Ks chunks {2w,2w+1} and Vs chunks {2w,2w+1}
  const u16* kgp[2]; const u16* vgp[2];
  int kc[2], vc[2];
#pragma unroll
  for (int i = 0; i < 2; i++) {
    int c = w * 2 + i;                 // 0..15
    int sl = c * 8 + (lane >> 3);
    int dg = (lane & 7) ^ (lane >> 3);
    kgp[i] = Kh + (size_t)sl * 1024 + dg * 8;
    kc[i] = c * 512;
    int dl = c * 4 + quad;
    int sg = (lane & 15) ^ (dl & 15);
    vgp[i] = Vh + (size_t)dl * 2048 + sg * 8;
    vc[i] = 8192 + c * 512;
  }

  auto issue_tile = [&](int buf, int t) {
    u16* dst = lds + buf * 16384;
    const size_t k0 = (size_t)t * 128;
#pragma unroll
    for (int i = 0; i < 2; i++) {
      async_load16(kgp[i] + k0 * 1024, dst + kc[i]);
      async_load16(vgp[i] + k0, dst + vc[i]);
    }
  };

  issue_tile(0, 0);                    // tile 0 loads overlap Q-frag loads

  // Q fragments: 32 q-rows/wave (B-operand: col=lane&15, k-octet=quad)
  const int qbase = q0 + qq * 32;
  bf16x8 qf[2][2];
#pragma unroll
  for (int qt = 0; qt < 2; qt++)
#pragma unroll
    for (int ks = 0; ks < 2; ks++)
      qf[qt][ks] = *(const bf16x8*)(Qh + (size_t)(qbase + qt * 16 + (lane & 15)) * 1024 +
                                    ks * 32 + quad * 8);

  bf16x8 onesf;
#pragma unroll
  for (int i = 0; i < 8; i++) onesf[i] = (__bf16)1.0f;
  const floatx4 zero4 = {};

  // K-fragment LDS offsets for this wave's s-half (4 slabs of 16 s)
  const int slot_k0 = quad ^ (lane & 7);
  const int slot_k1 = (4 + quad) ^ (lane & 7);
  const int koff0 = sh * 4096 + (lane & 15) * 64 + slot_k0 * 8;
  const int koff1 = sh * 4096 + (lane & 15) * 64 + slot_k1 * 8;
  // V-fragment offsets: MFMA k-octet Q holds s-octet sigma(Q)=bitrev2(Q)
  const int sq = ((quad & 1) << 1) | (quad >> 1);

  floatx4 o[2][4] = {};
  floatx4 lacc[2] = {};              // partial row sums (this s-half)

  // drain qf + tile-0 staging once so the loop's vmcnt discipline is clean
  asm volatile("s_waitcnt vmcnt(0)" ::: "memory");

#pragma unroll 2
  for (int t = 0; t < 16; ++t) {
    __builtin_amdgcn_s_barrier();        // tile t visible to all waves
    __builtin_amdgcn_sched_barrier(0);
    if (t < 15) issue_tile((t + 1) & 1, t + 1);   // in flight across compute
    const u16* Ksb = lds + (t & 1) * 16384;
    const u16* Vsb = Ksb + 8192;

    // QK for this wave's 4 slabs (batched: 16 MFMAs in flight)
    floatx4 st[4][2];
    __builtin_amdgcn_s_setprio(1);
#pragma unroll
    for (int si = 0; si < 4; si++) {
      bf16x8 kf0 = *(const bf16x8*)(Ksb + koff0 + si * 1024);
      bf16x8 kf1 = *(const bf16x8*)(Ksb + koff1 + si * 1024);
#pragma unroll
      for (int qt = 0; qt < 2; qt++)
        st[si][qt] = MFMA16(kf1, qf[qt][1], MFMA16(kf0, qf[qt][0], zero4));
    }
    __builtin_amdgcn_s_setprio(0);

    // p = exp2(st), pack to bf16 pairs: pa = regs{0,1}, pb = regs{2,3}
    unsigned pa[2][4], pb[2][4];
#pragma unroll
    for (int si = 0; si < 4; si++)
#pragma unroll
      for (int qt = 0; qt < 2; qt++) {
        pa[qt][si] = pack_bf2(fast_exp2(st[si][qt][0]), fast_exp2(st[si][qt][1]));
        pb[qt][si] = pack_bf2(fast_exp2(st[si][qt][2]), fast_exp2(st[si][qt][3]));
      }

    // in-register P->A-operand: swap quad pairs; resulting k-octet order is
    // sigma = (0,2,1,3), matched by the vf slot below.
    bf16x8 pf[2][2];
#pragma unroll
    for (int qt = 0; qt < 2; qt++)
#pragma unroll
      for (int ksl = 0; ksl < 2; ksl++) {
        unsigned x0 = pa[qt][2 * ksl], x1 = pa[qt][2 * ksl + 1];
        unsigned y0 = pb[qt][2 * ksl], y1 = pb[qt][2 * ksl + 1];
        asm("v_permlane16_swap_b32 %0, %1" : "+v"(x0), "+v"(x1));
        asm("v_permlane16_swap_b32 %0, %1" : "+v"(y0), "+v"(y1));
        union { unsigned u[4]; bf16x8 v; } uu;
        uu.u[0] = x0; uu.u[1] = y0; uu.u[2] = x1; uu.u[3] = y1;
        pf[qt][ksl] = uu.v;
      }

    // O += P . V over this s-half's two 32-s blocks
    __builtin_amdgcn_s_setprio(1);
#pragma unroll
    for (int ksl = 0; ksl < 2; ksl++) {
      int kb = sh * 2 + ksl;
      bf16x8 vf[4];
#pragma unroll
      for (int jt = 0; jt < 4; jt++) {
        int d = jt * 16 + (lane & 15);
        int slot = (kb * 4 + sq) ^ (d & 15);
        vf[jt] = *(const bf16x8*)(Vsb + d * 128 + slot * 8);
      }
#pragma unroll
      for (int qt = 0; qt < 2; qt++) {
#pragma unroll
        for (int jt = 0; jt < 4; jt++)
          o[qt][jt] = MFMA16(pf[qt][ksl], vf[jt], o[qt][jt]);
        lacc[qt] = MFMA16(pf[qt][ksl], onesf, lacc[qt]);
      }
    }
    __builtin_amdgcn_s_setprio(0);
    // own tile-(t+1) loads must be done before the next barrier
    asm volatile("s_waitcnt vmcnt(0)" ::: "memory");
  }

  // combine s-halves: sh==1 dumps O,l; sh==0 adds + stores.
  // dump region = lds[0..32KB) for O (2048 floatx4), [32KB..40KB) for l.
  __syncthreads();
  floatx4* dump  = (floatx4*)lds;
  floatx4* ldump = (floatx4*)(lds + 16384);
  if (sh == 1) {
    int base = qq * 512;
#pragma unroll
    for (int qt = 0; qt < 2; qt++)
#pragma unroll
      for (int jt = 0; jt < 4; jt++)
        dump[base + (qt * 4 + jt) * 64 + lane] = o[qt][jt];
#pragma unroll
    for (int qt = 0; qt < 2; qt++)
      ldump[qq * 128 + qt * 64 + lane] = lacc[qt];
  }
  __syncthreads();
  if (sh == 0) {
    int base = qq * 512;
#pragma unroll
    for (int qt = 0; qt < 2; qt++)
#pragma unroll
      for (int jt = 0; jt < 4; jt++)
        o[qt][jt] += dump[base + (qt * 4 + jt) * 64 + lane];
#pragma unroll
    for (int qt = 0; qt < 2; qt++)
      lacc[qt] += ldump[qq * 128 + qt * 64 + lane];
    // epilogue: ctx[b][s][h*64+d] bf16; lacc rows coincide with o rows
#pragma unroll
    for (int qt = 0; qt < 2; qt++)
#pragma unroll
      for (int r = 0; r < 4; r++) {
        float inv = 1.0f / lacc[qt][r];
        int s = qbase + qt * 16 + quad * 4 + r;
#pragma unroll
        for (int j = 0; j < 4; j++) {
          int c = h * 64 + j * 16 + (lane & 15);
          ctx[(size_t)(b * 2048 + s) * 1024 + c] = f2bf(o[qt][j][r] * inv);
        }
      }
  }
}

// ---- launch --------------------------------------------------------------
// ws layout (u16 elements, MM = 1024*1024):
//   [0,3MM)    WqT,WkT,WvT bf16        [3MM,4MM)  WoT bf16
//   [4MM,8MM)  x converted to bf16     [8MM,20MM) Q,K row-major (V slot unused)
//   [20MM,24MM) V^T bf16               [24MM,28MM) ctx bf16

extern "C" void kernel_launch(void* const* d_in, const int* in_sizes, int n_in,
                              void* d_out, int out_size, void* d_ws, size_t ws_size,
                              hipStream_t stream) {
  (void)in_sizes; (void)n_in; (void)out_size; (void)ws_size;
  const float* x  = (const float*)d_in[0];
  const float* Wq = (const float*)d_in[1];
  const float* Wk = (const float*)d_in[2];
  const float* Wv = (const float*)d_in[3];
  const float* Wo = (const float*)d_in[4];
  const float* bo = (const float*)d_in[5];
  u16* ws = (u16*)d_ws;
  const size_t MM = 1024 * 1024;
  u16* WT  = ws;             // 3 x [1024][1024] (Wq,Wk,Wv transposed)
  u16* WoT = ws + 3 * MM;    // [1024][1024]
  u16* Xb  = ws + 4 * MM;    // [4096][1024]
  u16* QKV = ws + 8 * MM;    // Q,K row-major [4096][1024] each
  u16* VTp = ws + 20 * MM;   // [32][64][2048]
  u16* CTX = ws + 24 * MM;   // [4096][1024]

  dim3 blk(256);
  prep_kernel<<<dim3(16, 16, 5), blk, 0, stream>>>(Wq, Wk, Wv, Wo, WT, x, Xb);
  gemm_qkv_kernel<<<dim3(16, 32, 1), blk, 0, stream>>>(Xb, WT, QKV, VTp);
  attn_kernel<<<dim3(512, 1, 1), dim3(512), 0, stream>>>(QKV, QKV + 4 * MM, VTp, CTX);
  gemm_o_kernel<<<dim3(16, 32, 1), blk, 0, stream>>>(CTX, WoT, bo, (float*)d_out);
}

// Round 13
// 171.338 us; speedup vs baseline: 1.0550x; 1.0280x over previous
//
#include <hip/hip_runtime.h>
#include <cstdint>

typedef unsigned short u16;
typedef __bf16 bf16x8 __attribute__((ext_vector_type(8)));
typedef __bf16 bf16x2 __attribute__((ext_vector_type(2)));
typedef float floatx4 __attribute__((ext_vector_type(4)));
typedef unsigned short u16x4 __attribute__((ext_vector_type(4)));
typedef unsigned short u16x8 __attribute__((ext_vector_type(8)));

#define MFMA16(a, b, c) __builtin_amdgcn_mfma_f32_16x16x32_bf16((a), (b), (c), 0, 0, 0)
// 0.125 * log2(e): folded into Q so softmax is exp2(st) with no per-elem mul.
#define QSCALE_LOG2E 0.18033688011112042f

// ---- helpers -------------------------------------------------------------
// R19: all f32->bf16 conversion via (__bf16) casts.  The previous helpers
// gated on __has_builtin(__builtin_amdgcn_cvt_pk_bf16_f32), which does NOT
// exist on gfx950 — so every conversion compiled to the ~5-op RNE bit-twiddle
// fallback (~320 VALU cyc/wave-iter in attn's hot loop alone; 64 f2bf/thread
// in the qkv epilogue).  Clang lowers bf16 fptrunc to v_cvt_pk_bf16_f32
// (RNE, auto-paired) — same rounding, ~10x fewer VALU ops.

typedef __attribute__((address_space(3))) void as3_void;
typedef __attribute__((address_space(1))) void as1_void;

static __device__ __forceinline__ void async_load16(const void* g, void* l) {
  __builtin_amdgcn_global_load_lds((as1_void*)(uintptr_t)g, (as3_void*)(uintptr_t)l,
                                   16, 0, 0);
}

static __device__ __forceinline__ u16 f2bf(float f) {
  union { __bf16 b; u16 u; } v;
  v.b = (__bf16)f;                   // RNE, lowers to v_cvt_pk_bf16_f32
  return v.u;
}

static __device__ __forceinline__ unsigned pack_bf2(float a, float b) {
  union { bf16x2 v; unsigned u; } x;
  x.v[0] = (__bf16)a;
  x.v[1] = (__bf16)b;                // compiler pairs into one cvt_pk
  return x.u;
}

static __device__ __forceinline__ u16x4 pack_bf4(float a, float b, float c, float d) {
  union { u16x4 v4; unsigned u2[2]; } u;
  u.u2[0] = pack_bf2(a, b);
  u.u2[1] = pack_bf2(c, d);
  return u.v4;
}

static __device__ __forceinline__ float fast_exp2(float x) {
#if __has_builtin(__builtin_amdgcn_exp2f)
  return __builtin_amdgcn_exp2f(x);
#else
  return exp2f(x);
#endif
}

// ---- fused: 4x weight transpose+convert (z=0..3) + x convert (z=4) -------

__global__ __launch_bounds__(256) void prep_kernel(
    const float* __restrict__ w0, const float* __restrict__ w1,
    const float* __restrict__ w2, const float* __restrict__ w3,
    u16* __restrict__ wout,
    const float* __restrict__ xin, u16* __restrict__ xout) {
  if (blockIdx.z == 4) {
    int blk = blockIdx.y * 16 + blockIdx.x;
    size_t base = (size_t)blk * 16384 + (size_t)threadIdx.x * 8;
#pragma unroll
    for (int r = 0; r < 8; r++) {
      size_t i = base + (size_t)r * 2048;
      float4 a = *(const float4*)(xin + i);
      float4 b = *(const float4*)(xin + i + 4);
      u16x8 o;
      o[0] = f2bf(a.x); o[1] = f2bf(a.y); o[2] = f2bf(a.z); o[3] = f2bf(a.w);
      o[4] = f2bf(b.x); o[5] = f2bf(b.y); o[6] = f2bf(b.z); o[7] = f2bf(b.w);
      *(u16x8*)(xout + i) = o;
    }
    return;
  }
  __shared__ u16 t[64][65];
  const float* in = (blockIdx.z == 0) ? w0 : (blockIdx.z == 1) ? w1
                    : (blockIdx.z == 2) ? w2 : w3;
  u16* oz = wout + (size_t)blockIdx.z * (1024 * 1024);
  const int tid = threadIdx.x;
  const int x = tid & 63, y0 = tid >> 6;
  const int bx = blockIdx.x * 64, by = blockIdx.y * 64;
#pragma unroll
  for (int p = 0; p < 16; p++) {
    int y = y0 + p * 4;
    t[y][x] = f2bf(in[(size_t)(by + y) * 1024 + bx + x]);
  }
  __syncthreads();
#pragma unroll
  for (int p = 0; p < 16; p++) {
    int r = y0 + p * 4;
    oz[(size_t)(bx + r) * 1024 + by + x] = t[x][r];
  }
}

// ---- fused QKV GEMM: Q,K,V tiles for one (bm,bn) in ONE block ------------
// R18: tile 128m x 64n, all 3 weights per block.  A-tile (Xb) staged ONCE
// per K-step feeds 3 GEMMs (24 MFMA/wave per 20 loads; A traffic / 3).
// Grid 512 blocks.  acc[3][4][2] = 96 VGPR, total ~160 < 256 cap.
// LDS: 40 KB dbuf arena + dedicated 9 KB tb2 (de-aliased; 49 KB still
// 3 blocks/CU since regs limit at 3 anyway).  V^T epilogue in two passes.

__global__ __launch_bounds__(256, 2) void gemm_qkv_kernel(
    const u16* __restrict__ A, const u16* __restrict__ BT,
    u16* __restrict__ out, u16* __restrict__ outVT) {
  __shared__ __align__(16) u16 sm[2 * 10240];   // 2 x (A 4096 + B 3*2048)
  __shared__ __align__(16) u16 tb2[64 * 72];    // V^T staging, one 64-s half
  const int tid = threadIdx.x;
  const int w = tid >> 6, lane = tid & 63;
  const int bm = blockIdx.y * 128, bn = blockIdx.x * 64;
  const int K = 1024, N = 1024;

  // staging: 20 chunks of 512 u16 (0..7 = A 16-row slabs, 8..19 = B z*4+cb);
  // wave w owns chunks 5w..5w+4.  Global src pre-swizzled to fragment slots.
  const u16* gp[5];
  int lo[5];
#pragma unroll
  for (int i = 0; i < 5; i++) {
    int c = w * 5 + i;
    if (c < 8) {
      int m = c * 16 + (lane >> 2);
      int kg = (lane & 3) ^ ((m >> 1) & 3);
      gp[i] = A + (size_t)(bm + m) * K + kg * 8;
      lo[i] = c * 512;
    } else {
      int cz = c - 8;                    // 0..11: z = cz>>2, cb = cz&3
      int z = cz >> 2;
      int n = (cz & 3) * 16 + (lane >> 2);
      int kg = (lane & 3) ^ ((n >> 1) & 3);
      gp[i] = BT + (size_t)z * N * K + (size_t)(bn + n) * K + kg * 8;
      lo[i] = 4096 + cz * 512;
    }
  }

  const int wm = (w >> 1) * 64, wn = (w & 1) * 32;
  floatx4 acc[3][4][2] = {};

  int a_off[4], b_off[2];
#pragma unroll
  for (int i = 0; i < 4; i++) {
    int m = wm + i * 16 + (lane & 15);
    a_off[i] = m * 32 + (((lane >> 4) ^ ((m >> 1) & 3)) * 8);
  }
#pragma unroll
  for (int j = 0; j < 2; j++) {
    int n = wn + j * 16 + (lane & 15);
    b_off[j] = n * 32 + (((lane >> 4) ^ ((n >> 1) & 3)) * 8);
  }

  auto issueQ = [&](int buf, int k0) {
    u16* base = sm + buf * 10240;
#pragma unroll
    for (int i = 0; i < 5; i++)
      async_load16(gp[i] + k0, base + lo[i]);
  };

  issueQ(0, 0);
  asm volatile("s_waitcnt vmcnt(0)" ::: "memory");
  __builtin_amdgcn_s_barrier();

#pragma unroll 2
  for (int kk = 0; kk < 32; ++kk) {
    if (kk < 31) issueQ((kk + 1) & 1, (kk + 1) * 32);
    const u16* Ab = sm + (kk & 1) * 10240;
    bf16x8 af[4];
#pragma unroll
    for (int i = 0; i < 4; i++) af[i] = *(const bf16x8*)(Ab + a_off[i]);
    __builtin_amdgcn_s_setprio(1);
#pragma unroll
    for (int z = 0; z < 3; z++) {
      const u16* Bb = Ab + 4096 + z * 2048;
      bf16x8 bf[2];
#pragma unroll
      for (int j = 0; j < 2; j++) bf[j] = *(const bf16x8*)(Bb + b_off[j]);
#pragma unroll
      for (int i = 0; i < 4; i++)
#pragma unroll
        for (int j = 0; j < 2; j++)
          acc[z][i][j] = MFMA16(af[i], bf[j], acc[z][i][j]);
    }
    __builtin_amdgcn_s_setprio(0);
    // own loads for kk+1 landed + own reads of this buf done, then converge
    asm volatile("s_waitcnt vmcnt(0) lgkmcnt(0)" ::: "memory");
    __builtin_amdgcn_s_barrier();
  }

  // epilogue: C/D layout col=lane&15, row=(lane>>4)*4+reg  [m89]
  const int roff = (lane >> 4) * 4;
  const int coff = lane & 15;

  // Q (scaled) and K row-major stores
#pragma unroll
  for (int z = 0; z < 2; z++) {
    const float sc = (z == 0) ? QSCALE_LOG2E : 1.0f;
    u16* outz = out + (size_t)z * 4096 * 1024;
#pragma unroll
    for (int i = 0; i < 4; i++) {
      int r0 = bm + wm + i * 16 + roff;
#pragma unroll
      for (int j = 0; j < 2; j++) {
        int c = bn + wn + j * 16 + coff;
#pragma unroll
        for (int r = 0; r < 4; r++)
          outz[(size_t)(r0 + r) * N + c] = f2bf(acc[z][i][j][r] * sc);
      }
    }
  }

  // V^T in two 64-s passes through the dedicated tb2 buffer.
  // Pass ha: waves with wm==ha*64 stage their 64 s-rows; all waves store.
  const int b = bm >> 11, s0 = bm & 2047;
#pragma unroll
  for (int ha = 0; ha < 2; ha++) {
    __syncthreads();
    if ((w >> 1) == ha) {
#pragma unroll
      for (int i = 0; i < 4; i++) {
        int s_l = i * 16 + roff;               // 0..63 within half
#pragma unroll
        for (int j = 0; j < 2; j++) {
          int c_local = wn + j * 16 + coff;    // 0..63
          u16x4 pk = pack_bf4(acc[2][i][j][0], acc[2][i][j][1],
                              acc[2][i][j][2], acc[2][i][j][3]);
          *(u16x4*)(tb2 + c_local * 72 + s_l) = pk;
        }
      }
    }
    __syncthreads();
    // store: 8 lanes cover one (h,d) row's 64 s (128B contiguous)
#pragma unroll
    for (int p = 0; p < 2; p++) {
      int row = p * 32 + (tid >> 3);           // 0..63
      int so = tid & 7;
      int cg = bn + row;
      int h = cg >> 6, d = cg & 63;
      u16x8 vv = *(const u16x8*)(tb2 + row * 72 + so * 8);
      *(u16x8*)(outVT + ((size_t)(b * 16 + h) * 64 + d) * 2048 +
                s0 + ha * 64 + so * 8) = vv;
    }
  }
}

// ---- O GEMM: out[4096][1024] f32 = CTX @ Wo + bo -------------------------
// 128m x 64n tile, BK=32, 4 waves (2x2 of 64x32) -> 512 blocks = 2/CU.
// Double-buffer + raw-barrier structure (R12).

__global__ __launch_bounds__(256, 2) void gemm_o_kernel(
    const u16* __restrict__ A, const u16* __restrict__ BT,
    const float* __restrict__ bias, float* __restrict__ out) {
  __shared__ u16 As[2 * 4096];
  __shared__ u16 Bs[2 * 2048];
  const int tid = threadIdx.x;
  const int w = tid >> 6, lane = tid & 63;
  const int bm = blockIdx.y * 128, bn = blockIdx.x * 64;
  const int K = 1024, N = 1024;

  const u16* gp[3];
  u16* ldp[2][3];
#pragma unroll
  for (int i = 0; i < 3; i++) {
    int c = w * 3 + i;
    if (c < 8) {
      int m = c * 16 + (lane >> 2);
      int kg = (lane & 3) ^ ((m >> 1) & 3);
      gp[i] = A + (size_t)(bm + m) * K + kg * 8;
      ldp[0][i] = As + c * 512;
      ldp[1][i] = As + 4096 + c * 512;
    } else {
      int cb = c - 8;
      int n = cb * 16 + (lane >> 2);
      int kg = (lane & 3) ^ ((n >> 1) & 3);
      gp[i] = BT + (size_t)(bn + n) * K + kg * 8;
      ldp[0][i] = Bs + cb * 512;
      ldp[1][i] = Bs + 2048 + cb * 512;
    }
  }

  const int wm = (w >> 1) * 64, wn = (w & 1) * 32;
  floatx4 acc[4][2] = {};

  int a_off[4], b_off[2];
#pragma unroll
  for (int i = 0; i < 4; i++) {
    int m = wm + i * 16 + (lane & 15);
    a_off[i] = m * 32 + (((lane >> 4) ^ ((m >> 1) & 3)) * 8);
  }
#pragma unroll
  for (int j = 0; j < 2; j++) {
    int n = wn + j * 16 + (lane & 15);
    b_off[j] = n * 32 + (((lane >> 4) ^ ((n >> 1) & 3)) * 8);
  }

  auto issueO = [&](int buf, int k0) {
#pragma unroll
    for (int i = 0; i < 3; i++)
      async_load16(gp[i] + k0, buf ? ldp[1][i] : ldp[0][i]);
  };

  issueO(0, 0);
  asm volatile("s_waitcnt vmcnt(0)" ::: "memory");
  __builtin_amdgcn_s_barrier();

#pragma unroll 2
  for (int kk = 0; kk < 32; ++kk) {
    if (kk < 31) issueO((kk + 1) & 1, (kk + 1) * 32);
    const u16* Ab = As + (kk & 1) * 4096;
    const u16* Bb = Bs + (kk & 1) * 2048;
    bf16x8 af[4], bf[2];
#pragma unroll
    for (int i = 0; i < 4; i++) af[i] = *(const bf16x8*)(Ab + a_off[i]);
#pragma unroll
    for (int j = 0; j < 2; j++) bf[j] = *(const bf16x8*)(Bb + b_off[j]);
    __builtin_amdgcn_s_setprio(1);
#pragma unroll
    for (int i = 0; i < 4; i++)
#pragma unroll
      for (int j = 0; j < 2; j++)
        acc[i][j] = MFMA16(af[i], bf[j], acc[i][j]);
    __builtin_amdgcn_s_setprio(0);
    asm volatile("s_waitcnt vmcnt(0) lgkmcnt(0)" ::: "memory");
    __builtin_amdgcn_s_barrier();
  }

  const int roff = (lane >> 4) * 4;
  const int coff = lane & 15;
#pragma unroll
  for (int i = 0; i < 4; i++) {
    int r0 = bm + wm + i * 16 + roff;
#pragma unroll
    for (int j = 0; j < 2; j++) {
      int c = bn + wn + j * 16 + coff;
      float bv = bias[c];
#pragma unroll
      for (int r = 0; r < 4; r++)
        out[(size_t)(r0 + r) * N + c] = acc[i][j][r] + bv;
    }
  }
}

// ---- flash attention (no-max softmax, 512-thread blocks, s-split pairs) --
// Q (pre-scaled), K: [b*2048+s][1024] row-major bf16, head at col h*64.
// VT: [bh][64][2048] bf16.  ctx: [b][s][1024] bf16.
// Block = 8 waves over a 128q x 128s tile: wave (qq,sh) = q-quarter qq
// (32 rows in registers as B-operand) x s-half sh (64 cols).
//
// Verified at 50.2-53.1 us.  R12/R13/R14 pipeline-deepening all spilled:
// per-wave state ~120 regs on the UNIFIED gfx950 VGPR/AGPR file caps
// occupancy at 4 waves/SIMD; do not add live state across the QK phase.
// In-register P (permlane16_swap, sigma=(0,2,1,3) absorbed into vf slot);
// K/V double-buffered, one raw barrier + one vmcnt(0) per iteration.
// R19: pack path now compiles to v_cvt_pk_bf16_f32 (see helper comment).

__global__ __launch_bounds__(512, 4) void attn_kernel(
    const u16* __restrict__ Q, const u16* __restrict__ Kx,
    const u16* __restrict__ VT, u16* __restrict__ ctx) {
  // arena: 2 x { Ks [128s][64d] | Vs [64d][128s] } = 64 KB
  __shared__ __align__(16) u16 lds[32768];
  const int tid = threadIdx.x;
  const int w = tid >> 6, lane = tid & 63;
  const int qq = w >> 1, sh = w & 1;
  const int quad = lane >> 4;
  const int bid = blockIdx.x;
  const int bh = (bid >> 7) * 8 + (bid & 7);      // XCD-pinned head group
  const int q0 = ((bid >> 3) & 15) * 128;
  const int b = bh >> 4, h = bh & 15;
  const u16* Qh = Q + (size_t)b * 2048 * 1024 + h * 64;
  const u16* Kh = Kx + (size_t)b * 2048 * 1024 + h * 64;
  const u16* Vh = VT + (size_t)bh * 64 * 2048;

  // staging: wave w owns Ks chunks {2w,2w+1} and Vs chunks {2w,2w+1}
  const u16* kgp[2]; const u16* vgp[2];
  int kc[2], vc[2];
#pragma unroll
  for (int i = 0; i < 2; i++) {
    int c = w * 2 + i;                 // 0..15
    int sl = c * 8 + (lane >> 3);
    int dg = (lane & 7) ^ (lane >> 3);
    kgp[i] = Kh + (size_t)sl * 1024 + dg * 8;
    kc[i] = c * 512;
    int dl = c * 4 + quad;
    int sg = (lane & 15) ^ (dl & 15);
    vgp[i] = Vh + (size_t)dl * 2048 + sg * 8;
    vc[i] = 8192 + c * 512;
  }

  auto issue_tile = [&](int buf, int t) {
    u16* dst = lds + buf * 16384;
    const size_t k0 = (size_t)t * 128;
#pragma unroll
    for (int i = 0; i < 2; i++) {
      async_load16(kgp[i] + k0 * 1024, dst + kc[i]);
      async_load16(vgp[i] + k0, dst + vc[i]);
    }
  };

  issue_tile(0, 0);                    // tile 0 loads overlap Q-frag loads

  // Q fragments: 32 q-rows/wave (B-operand: col=lane&15, k-octet=quad)
  const int qbase = q0 + qq * 32;
  bf16x8 qf[2][2];
#pragma unroll
  for (int qt = 0; qt < 2; qt++)
#pragma unroll
    for (int ks = 0; ks < 2; ks++)
      qf[qt][ks] = *(const bf16x8*)(Qh + (size_t)(qbase + qt * 16 + (lane & 15)) * 1024 +
                                    ks * 32 + quad * 8);

  bf16x8 onesf;
#pragma unroll
  for (int i = 0; i < 8; i++) onesf[i] = (__bf16)1.0f;
  const floatx4 zero4 = {};

  // K-fragment LDS offsets for this wave's s-half (4 slabs of 16 s)
  const int slot_k0 = quad ^ (lane & 7);
  const int slot_k1 = (4 + quad) ^ (lane & 7);
  const int koff0 = sh * 4096 + (lane & 15) * 64 + slot_k0 * 8;
  const int koff1 = sh * 4096 + (lane & 15) * 64 + slot_k1 * 8;
  // V-fragment offsets: MFMA k-octet Q holds s-octet sigma(Q)=bitrev2(Q)
  const int sq = ((quad & 1) << 1) | (quad >> 1);

  floatx4 o[2][4] = {};
  floatx4 lacc[2] = {};              // partial row sums (this s-half)

  // drain qf + tile-0 staging once so the loop's vmcnt discipline is clean
  asm volatile("s_waitcnt vmcnt(0)" ::: "memory");

#pragma unroll 2
  for (int t = 0; t < 16; ++t) {
    __builtin_amdgcn_s_barrier();        // tile t visible to all waves
    __builtin_amdgcn_sched_barrier(0);
    if (t < 15) issue_tile((t + 1) & 1, t + 1);   // in flight across compute
    const u16* Ksb = lds + (t & 1) * 16384;
    const u16* Vsb = Ksb + 8192;

    // QK for this wave's 4 slabs (batched: 16 MFMAs in flight)
    floatx4 st[4][2];
    __builtin_amdgcn_s_setprio(1);
#pragma unroll
    for (int si = 0; si < 4; si++) {
      bf16x8 kf0 = *(const bf16x8*)(Ksb + koff0 + si * 1024);
      bf16x8 kf1 = *(const bf16x8*)(Ksb + koff1 + si * 1024);
#pragma unroll
      for (int qt = 0; qt < 2; qt++)
        st[si][qt] = MFMA16(kf1, qf[qt][1], MFMA16(kf0, qf[qt][0], zero4));
    }
    __builtin_amdgcn_s_setprio(0);

    // p = exp2(st), pack to bf16 pairs: pa = regs{0,1}, pb = regs{2,3}
    unsigned pa[2][4], pb[2][4];
#pragma unroll
    for (int si = 0; si < 4; si++)
#pragma unroll
      for (int qt = 0; qt < 2; qt++) {
        pa[qt][si] = pack_bf2(fast_exp2(st[si][qt][0]), fast_exp2(st[si][qt][1]));
        pb[qt][si] = pack_bf2(fast_exp2(st[si][qt][2]), fast_exp2(st[si][qt][3]));
      }

    // in-register P->A-operand: swap quad pairs; resulting k-octet order is
    // sigma = (0,2,1,3), matched by the vf slot below.
    bf16x8 pf[2][2];
#pragma unroll
    for (int qt = 0; qt < 2; qt++)
#pragma unroll
      for (int ksl = 0; ksl < 2; ksl++) {
        unsigned x0 = pa[qt][2 * ksl], x1 = pa[qt][2 * ksl + 1];
        unsigned y0 = pb[qt][2 * ksl], y1 = pb[qt][2 * ksl + 1];
        asm("v_permlane16_swap_b32 %0, %1" : "+v"(x0), "+v"(x1));
        asm("v_permlane16_swap_b32 %0, %1" : "+v"(y0), "+v"(y1));
        union { unsigned u[4]; bf16x8 v; } uu;
        uu.u[0] = x0; uu.u[1] = y0; uu.u[2] = x1; uu.u[3] = y1;
        pf[qt][ksl] = uu.v;
      }

    // O += P . V over this s-half's two 32-s blocks
    __builtin_amdgcn_s_setprio(1);
#pragma unroll
    for (int ksl = 0; ksl < 2; ksl++) {
      int kb = sh * 2 + ksl;
      bf16x8 vf[4];
#pragma unroll
      for (int jt = 0; jt < 4; jt++) {
        int d = jt * 16 + (lane & 15);
        int slot = (kb * 4 + sq) ^ (d & 15);
        vf[jt] = *(const bf16x8*)(Vsb + d * 128 + slot * 8);
      }
#pragma unroll
      for (int qt = 0; qt < 2; qt++) {
#pragma unroll
        for (int jt = 0; jt < 4; jt++)
          o[qt][jt] = MFMA16(pf[qt][ksl], vf[jt], o[qt][jt]);
        lacc[qt] = MFMA16(pf[qt][ksl], onesf, lacc[qt]);
      }
    }
    __builtin_amdgcn_s_setprio(0);
    // own tile-(t+1) loads must be done before the next barrier
    asm volatile("s_waitcnt vmcnt(0)" ::: "memory");
  }

  // combine s-halves: sh==1 dumps O,l; sh==0 adds + stores.
  // dump region = lds[0..32KB) for O (2048 floatx4), [32KB..40KB) for l.
  __syncthreads();
  floatx4* dump  = (floatx4*)lds;
  floatx4* ldump = (floatx4*)(lds + 16384);
  if (sh == 1) {
    int base = qq * 512;
#pragma unroll
    for (int qt = 0; qt < 2; qt++)
#pragma unroll
      for (int jt = 0; jt < 4; jt++)
        dump[base + (qt * 4 + jt) * 64 + lane] = o[qt][jt];
#pragma unroll
    for (int qt = 0; qt < 2; qt++)
      ldump[qq * 128 + qt * 64 + lane] = lacc[qt];
  }
  __syncthreads();
  if (sh == 0) {
    int base = qq * 512;
#pragma unroll
    for (int qt = 0; qt < 2; qt++)
#pragma unroll
      for (int jt = 0; jt < 4; jt++)
        o[qt][jt] += dump[base + (qt * 4 + jt) * 64 + lane];
#pragma unroll
    for (int qt = 0; qt < 2; qt++)
      lacc[qt] += ldump[qq * 128 + qt * 64 + lane];
    // epilogue: ctx[b][s][h*64+d] bf16; lacc rows coincide with o rows
#pragma unroll
    for (int qt = 0; qt < 2; qt++)
#pragma unroll
      for (int r = 0; r < 4; r++) {
        float inv = 1.0f / lacc[qt][r];
        int s = qbase + qt * 16 + quad * 4 + r;
#pragma unroll
        for (int j = 0; j < 4; j++) {
          int c = h * 64 + j * 16 + (lane & 15);
          ctx[(size_t)(b * 2048 + s) * 1024 + c] = f2bf(o[qt][j][r] * inv);
        }
      }
  }
}

// ---- launch --------------------------------------------------------------
// ws layout (u16 elements, MM = 1024*1024):
//   [0,3MM)    WqT,WkT,WvT bf16        [3MM,4MM)  WoT bf16
//   [4MM,8MM)  x converted to bf16     [8MM,20MM) Q,K row-major (V slot unused)
//   [20MM,24MM) V^T bf16               [24MM,28MM) ctx bf16

extern "C" void kernel_launch(void* const* d_in, const int* in_sizes, int n_in,
                              void* d_out, int out_size, void* d_ws, size_t ws_size,
                              hipStream_t stream) {
  (void)in_sizes; (void)n_in; (void)out_size; (void)ws_size;
  const float* x  = (const float*)d_in[0];
  const float* Wq = (const float*)d_in[1];
  const float* Wk = (const float*)d_in[2];
  const float* Wv = (const float*)d_in[3];
  const float* Wo = (const float*)d_in[4];
  const float* bo = (const float*)d_in[5];
  u16* ws = (u16*)d_ws;
  const size_t MM = 1024 * 1024;
  u16* WT  = ws;             // 3 x [1024][1024] (Wq,Wk,Wv transposed)
  u16* WoT = ws + 3 * MM;    // [1024][1024]
  u16* Xb  = ws + 4 * MM;    // [4096][1024]
  u16* QKV = ws + 8 * MM;    // Q,K row-major [4096][1024] each
  u16* VTp = ws + 20 * MM;   // [32][64][2048]
  u16* CTX = ws + 24 * MM;   // [4096][1024]

  dim3 blk(256);
  prep_kernel<<<dim3(16, 16, 5), blk, 0, stream>>>(Wq, Wk, Wv, Wo, WT, x, Xb);
  gemm_qkv_kernel<<<dim3(16, 32, 1), blk, 0, stream>>>(Xb, WT, QKV, VTp);
  attn_kernel<<<dim3(512, 1, 1), dim3(512), 0, stream>>>(QKV, QKV + 4 * MM, VTp, CTX);
  gemm_o_kernel<<<dim3(16, 32, 1), blk, 0, stream>>>(CTX, WoT, bo, (float*)d_out);
}

// Round 14
// 170.329 us; speedup vs baseline: 1.0613x; 1.0059x over previous
//
#include <hip/hip_runtime.h>
#include <cstdint>

typedef unsigned short u16;
typedef __bf16 bf16x8 __attribute__((ext_vector_type(8)));
typedef __bf16 bf16x2 __attribute__((ext_vector_type(2)));
typedef float floatx4 __attribute__((ext_vector_type(4)));
typedef unsigned short u16x4 __attribute__((ext_vector_type(4)));
typedef unsigned short u16x8 __attribute__((ext_vector_type(8)));

#define MFMA16(a, b, c) __builtin_amdgcn_mfma_f32_16x16x32_bf16((a), (b), (c), 0, 0, 0)
// 0.125 * log2(e): folded into Q so softmax is exp2(st) with no per-elem mul.
#define QSCALE_LOG2E 0.18033688011112042f

// ---- helpers -------------------------------------------------------------
// R19: all f32->bf16 via (__bf16) casts — clang lowers to v_cvt_pk_bf16_f32
// (RNE, auto-paired).  The old __has_builtin(cvt_pk) gate always took the
// ~5-op bit-twiddle fallback (builtin doesn't exist on gfx950): −11us attn.

typedef __attribute__((address_space(3))) void as3_void;
typedef __attribute__((address_space(1))) void as1_void;

static __device__ __forceinline__ void async_load16(const void* g, void* l) {
  __builtin_amdgcn_global_load_lds((as1_void*)(uintptr_t)g, (as3_void*)(uintptr_t)l,
                                   16, 0, 0);
}

static __device__ __forceinline__ u16 f2bf(float f) {
  union { __bf16 b; u16 u; } v;
  v.b = (__bf16)f;                   // RNE, lowers to v_cvt_pk_bf16_f32
  return v.u;
}

static __device__ __forceinline__ unsigned pack_bf2(float a, float b) {
  union { bf16x2 v; unsigned u; } x;
  x.v[0] = (__bf16)a;
  x.v[1] = (__bf16)b;                // compiler pairs into one cvt_pk
  return x.u;
}

static __device__ __forceinline__ u16x4 pack_bf4(float a, float b, float c, float d) {
  union { u16x4 v4; unsigned u2[2]; } u;
  u.u2[0] = pack_bf2(a, b);
  u.u2[1] = pack_bf2(c, d);
  return u.v4;
}

static __device__ __forceinline__ float fast_exp2(float x) {
#if __has_builtin(__builtin_amdgcn_exp2f)
  return __builtin_amdgcn_exp2f(x);
#else
  return exp2f(x);
#endif
}

// ---- fused: 4x weight transpose+convert (z=0..3) + x convert (z=4) -------

__global__ __launch_bounds__(256) void prep_kernel(
    const float* __restrict__ w0, const float* __restrict__ w1,
    const float* __restrict__ w2, const float* __restrict__ w3,
    u16* __restrict__ wout,
    const float* __restrict__ xin, u16* __restrict__ xout) {
  if (blockIdx.z == 4) {
    int blk = blockIdx.y * 16 + blockIdx.x;
    size_t base = (size_t)blk * 16384 + (size_t)threadIdx.x * 8;
#pragma unroll
    for (int r = 0; r < 8; r++) {
      size_t i = base + (size_t)r * 2048;
      float4 a = *(const float4*)(xin + i);
      float4 b = *(const float4*)(xin + i + 4);
      u16x8 o;
      o[0] = f2bf(a.x); o[1] = f2bf(a.y); o[2] = f2bf(a.z); o[3] = f2bf(a.w);
      o[4] = f2bf(b.x); o[5] = f2bf(b.y); o[6] = f2bf(b.z); o[7] = f2bf(b.w);
      *(u16x8*)(xout + i) = o;
    }
    return;
  }
  __shared__ u16 t[64][65];
  const float* in = (blockIdx.z == 0) ? w0 : (blockIdx.z == 1) ? w1
                    : (blockIdx.z == 2) ? w2 : w3;
  u16* oz = wout + (size_t)blockIdx.z * (1024 * 1024);
  const int tid = threadIdx.x;
  const int x = tid & 63, y0 = tid >> 6;
  const int bx = blockIdx.x * 64, by = blockIdx.y * 64;
#pragma unroll
  for (int p = 0; p < 16; p++) {
    int y = y0 + p * 4;
    t[y][x] = f2bf(in[(size_t)(by + y) * 1024 + bx + x]);
  }
  __syncthreads();
#pragma unroll
  for (int p = 0; p < 16; p++) {
    int r = y0 + p * 4;
    oz[(size_t)(bx + r) * 1024 + by + x] = t[x][r];
  }
}

// ---- fused QKV GEMM: Q,K,V tiles for one (bm,bn) in ONE block ------------
// R18: tile 128m x 64n, all 3 weights per block.  A-tile (Xb) staged ONCE
// per K-step feeds 3 GEMMs (24 MFMA/wave per 20 loads; A traffic / 3).
// Grid 512 blocks.  acc[3][4][2] = 96 VGPR, total ~160 < 256 cap.
// LDS: 40 KB dbuf arena + dedicated 9 KB tb2.  V^T epilogue in two passes.

__global__ __launch_bounds__(256, 2) void gemm_qkv_kernel(
    const u16* __restrict__ A, const u16* __restrict__ BT,
    u16* __restrict__ out, u16* __restrict__ outVT) {
  __shared__ __align__(16) u16 sm[2 * 10240];   // 2 x (A 4096 + B 3*2048)
  __shared__ __align__(16) u16 tb2[64 * 72];    // V^T staging, one 64-s half
  const int tid = threadIdx.x;
  const int w = tid >> 6, lane = tid & 63;
  const int bm = blockIdx.y * 128, bn = blockIdx.x * 64;
  const int K = 1024, N = 1024;

  // staging: 20 chunks of 512 u16 (0..7 = A 16-row slabs, 8..19 = B z*4+cb);
  // wave w owns chunks 5w..5w+4.  Global src pre-swizzled to fragment slots.
  const u16* gp[5];
  int lo[5];
#pragma unroll
  for (int i = 0; i < 5; i++) {
    int c = w * 5 + i;
    if (c < 8) {
      int m = c * 16 + (lane >> 2);
      int kg = (lane & 3) ^ ((m >> 1) & 3);
      gp[i] = A + (size_t)(bm + m) * K + kg * 8;
      lo[i] = c * 512;
    } else {
      int cz = c - 8;                    // 0..11: z = cz>>2, cb = cz&3
      int z = cz >> 2;
      int n = (cz & 3) * 16 + (lane >> 2);
      int kg = (lane & 3) ^ ((n >> 1) & 3);
      gp[i] = BT + (size_t)z * N * K + (size_t)(bn + n) * K + kg * 8;
      lo[i] = 4096 + cz * 512;
    }
  }

  const int wm = (w >> 1) * 64, wn = (w & 1) * 32;
  floatx4 acc[3][4][2] = {};

  int a_off[4], b_off[2];
#pragma unroll
  for (int i = 0; i < 4; i++) {
    int m = wm + i * 16 + (lane & 15);
    a_off[i] = m * 32 + (((lane >> 4) ^ ((m >> 1) & 3)) * 8);
  }
#pragma unroll
  for (int j = 0; j < 2; j++) {
    int n = wn + j * 16 + (lane & 15);
    b_off[j] = n * 32 + (((lane >> 4) ^ ((n >> 1) & 3)) * 8);
  }

  auto issueQ = [&](int buf, int k0) {
    u16* base = sm + buf * 10240;
#pragma unroll
    for (int i = 0; i < 5; i++)
      async_load16(gp[i] + k0, base + lo[i]);
  };

  issueQ(0, 0);
  asm volatile("s_waitcnt vmcnt(0)" ::: "memory");
  __builtin_amdgcn_s_barrier();

#pragma unroll 2
  for (int kk = 0; kk < 32; ++kk) {
    if (kk < 31) issueQ((kk + 1) & 1, (kk + 1) * 32);
    const u16* Ab = sm + (kk & 1) * 10240;
    bf16x8 af[4];
#pragma unroll
    for (int i = 0; i < 4; i++) af[i] = *(const bf16x8*)(Ab + a_off[i]);
    __builtin_amdgcn_s_setprio(1);
#pragma unroll
    for (int z = 0; z < 3; z++) {
      const u16* Bb = Ab + 4096 + z * 2048;
      bf16x8 bf[2];
#pragma unroll
      for (int j = 0; j < 2; j++) bf[j] = *(const bf16x8*)(Bb + b_off[j]);
#pragma unroll
      for (int i = 0; i < 4; i++)
#pragma unroll
        for (int j = 0; j < 2; j++)
          acc[z][i][j] = MFMA16(af[i], bf[j], acc[z][i][j]);
    }
    __builtin_amdgcn_s_setprio(0);
    // own loads for kk+1 landed + own reads of this buf done, then converge
    asm volatile("s_waitcnt vmcnt(0) lgkmcnt(0)" ::: "memory");
    __builtin_amdgcn_s_barrier();
  }

  // epilogue: C/D layout col=lane&15, row=(lane>>4)*4+reg  [m89]
  const int roff = (lane >> 4) * 4;
  const int coff = lane & 15;

  // Q (scaled) and K row-major stores
#pragma unroll
  for (int z = 0; z < 2; z++) {
    const float sc = (z == 0) ? QSCALE_LOG2E : 1.0f;
    u16* outz = out + (size_t)z * 4096 * 1024;
#pragma unroll
    for (int i = 0; i < 4; i++) {
      int r0 = bm + wm + i * 16 + roff;
#pragma unroll
      for (int j = 0; j < 2; j++) {
        int c = bn + wn + j * 16 + coff;
#pragma unroll
        for (int r = 0; r < 4; r++)
          outz[(size_t)(r0 + r) * N + c] = f2bf(acc[z][i][j][r] * sc);
      }
    }
  }

  // V^T in two 64-s passes through the dedicated tb2 buffer.
  // Pass ha: waves with wm==ha*64 stage their 64 s-rows; all waves store.
  const int b = bm >> 11, s0 = bm & 2047;
#pragma unroll
  for (int ha = 0; ha < 2; ha++) {
    __syncthreads();
    if ((w >> 1) == ha) {
#pragma unroll
      for (int i = 0; i < 4; i++) {
        int s_l = i * 16 + roff;               // 0..63 within half
#pragma unroll
        for (int j = 0; j < 2; j++) {
          int c_local = wn + j * 16 + coff;    // 0..63
          u16x4 pk = pack_bf4(acc[2][i][j][0], acc[2][i][j][1],
                              acc[2][i][j][2], acc[2][i][j][3]);
          *(u16x4*)(tb2 + c_local * 72 + s_l) = pk;
        }
      }
    }
    __syncthreads();
    // store: 8 lanes cover one (h,d) row's 64 s (128B contiguous)
#pragma unroll
    for (int p = 0; p < 2; p++) {
      int row = p * 32 + (tid >> 3);           // 0..63
      int so = tid & 7;
      int cg = bn + row;
      int h = cg >> 6, d = cg & 63;
      u16x8 vv = *(const u16x8*)(tb2 + row * 72 + so * 8);
      *(u16x8*)(outVT + ((size_t)(b * 16 + h) * 64 + d) * 2048 +
                s0 + ha * 64 + so * 8) = vv;
    }
  }
}

// ---- O GEMM: out[4096][1024] f32 = CTX @ Wo + bo -------------------------
// 128m x 64n tile, BK=32, 4 waves (2x2 of 64x32) -> 512 blocks = 2/CU.
// Double-buffer + raw-barrier structure (R12).

__global__ __launch_bounds__(256, 2) void gemm_o_kernel(
    const u16* __restrict__ A, const u16* __restrict__ BT,
    const float* __restrict__ bias, float* __restrict__ out) {
  __shared__ u16 As[2 * 4096];
  __shared__ u16 Bs[2 * 2048];
  const int tid = threadIdx.x;
  const int w = tid >> 6, lane = tid & 63;
  const int bm = blockIdx.y * 128, bn = blockIdx.x * 64;
  const int K = 1024, N = 1024;

  const u16* gp[3];
  u16* ldp[2][3];
#pragma unroll
  for (int i = 0; i < 3; i++) {
    int c = w * 3 + i;
    if (c < 8) {
      int m = c * 16 + (lane >> 2);
      int kg = (lane & 3) ^ ((m >> 1) & 3);
      gp[i] = A + (size_t)(bm + m) * K + kg * 8;
      ldp[0][i] = As + c * 512;
      ldp[1][i] = As + 4096 + c * 512;
    } else {
      int cb = c - 8;
      int n = cb * 16 + (lane >> 2);
      int kg = (lane & 3) ^ ((n >> 1) & 3);
      gp[i] = BT + (size_t)(bn + n) * K + kg * 8;
      ldp[0][i] = Bs + cb * 512;
      ldp[1][i] = Bs + 2048 + cb * 512;
    }
  }

  const int wm = (w >> 1) * 64, wn = (w & 1) * 32;
  floatx4 acc[4][2] = {};

  int a_off[4], b_off[2];
#pragma unroll
  for (int i = 0; i < 4; i++) {
    int m = wm + i * 16 + (lane & 15);
    a_off[i] = m * 32 + (((lane >> 4) ^ ((m >> 1) & 3)) * 8);
  }
#pragma unroll
  for (int j = 0; j < 2; j++) {
    int n = wn + j * 16 + (lane & 15);
    b_off[j] = n * 32 + (((lane >> 4) ^ ((n >> 1) & 3)) * 8);
  }

  auto issueO = [&](int buf, int k0) {
#pragma unroll
    for (int i = 0; i < 3; i++)
      async_load16(gp[i] + k0, buf ? ldp[1][i] : ldp[0][i]);
  };

  issueO(0, 0);
  asm volatile("s_waitcnt vmcnt(0)" ::: "memory");
  __builtin_amdgcn_s_barrier();

#pragma unroll 2
  for (int kk = 0; kk < 32; ++kk) {
    if (kk < 31) issueO((kk + 1) & 1, (kk + 1) * 32);
    const u16* Ab = As + (kk & 1) * 4096;
    const u16* Bb = Bs + (kk & 1) * 2048;
    bf16x8 af[4], bf[2];
#pragma unroll
    for (int i = 0; i < 4; i++) af[i] = *(const bf16x8*)(Ab + a_off[i]);
#pragma unroll
    for (int j = 0; j < 2; j++) bf[j] = *(const bf16x8*)(Bb + b_off[j]);
    __builtin_amdgcn_s_setprio(1);
#pragma unroll
    for (int i = 0; i < 4; i++)
#pragma unroll
      for (int j = 0; j < 2; j++)
        acc[i][j] = MFMA16(af[i], bf[j], acc[i][j]);
    __builtin_amdgcn_s_setprio(0);
    asm volatile("s_waitcnt vmcnt(0) lgkmcnt(0)" ::: "memory");
    __builtin_amdgcn_s_barrier();
  }

  const int roff = (lane >> 4) * 4;
  const int coff = lane & 15;
#pragma unroll
  for (int i = 0; i < 4; i++) {
    int r0 = bm + wm + i * 16 + roff;
#pragma unroll
    for (int j = 0; j < 2; j++) {
      int c = bn + wn + j * 16 + coff;
      float bv = bias[c];
#pragma unroll
      for (int r = 0; r < 4; r++)
        out[(size_t)(r0 + r) * N + c] = acc[i][j][r] + bv;
    }
  }
}

// ---- flash attention (no-max softmax, 512-thread blocks) -----------------
// Q (pre-scaled), K: [b*2048+s][1024] row-major bf16, head at col h*64.
// VT: [bh][64][2048] bf16.  ctx: [b][s][1024] bf16.
// Block = 8 waves over a 128q x 64s tile-step: wave (qq,sh) = q-quarter qq
// (32 rows in registers as B-operand) x s-half sh (32 cols of the 64).
//
// R20: KVBLK 128 -> 64 (the R14 occupancy idea done right).  Post-R19 the
// kernel allocates exactly 64 VGPR, so the ONLY occupancy limiter was LDS
// (64 KB -> 2 blocks/CU = 16 waves).  Halving the K/V tile (2 x 16 KB
// staging; 40 KB total with epilogue dump) gives 4 blocks/CU = 32 waves/CU
// at unchanged launch_bounds(512,4) — no register-cap change, no spill risk.
// 32 iterations of the same schedule; all swizzle algebra carries with
// halved s-extents (V slot XOR over 8 octets -> 2-way LDS aliasing, free
// per m136).  Do not add live state across QK (R12/R13/R14 spills).

__global__ __launch_bounds__(512, 4) void attn_kernel(
    const u16* __restrict__ Q, const u16* __restrict__ Kx,
    const u16* __restrict__ VT, u16* __restrict__ ctx) {
  // arena: 2 x { Ks [64s][64d] | Vs [64d][64s] } = 32 KB staging;
  // epilogue dump uses 40 KB (o 32 KB + lacc 8 KB)
  __shared__ __align__(16) u16 lds[20480];
  const int tid = threadIdx.x;
  const int w = tid >> 6, lane = tid & 63;
  const int qq = w >> 1, sh = w & 1;
  const int quad = lane >> 4;
  const int bid = blockIdx.x;
  const int bh = (bid >> 7) * 8 + (bid & 7);      // XCD-pinned head group
  const int q0 = ((bid >> 3) & 15) * 128;
  const int b = bh >> 4, h = bh & 15;
  const u16* Qh = Q + (size_t)b * 2048 * 1024 + h * 64;
  const u16* Kh = Kx + (size_t)b * 2048 * 1024 + h * 64;
  const u16* Vh = VT + (size_t)bh * 64 * 2048;

  // staging: wave w owns K chunk w (8 s-rows) + V chunk w (8 d-rows)
  const int slK = w * 8 + (lane >> 3);          // s-row 0..63
  const int dgK = (lane & 7) ^ (lane >> 3);     // d-octet slot (XOR s&7)
  const u16* kgp = Kh + (size_t)slK * 1024 + dgK * 8;
  const int kc = w * 512;
  const int dlV = w * 8 + (lane >> 3);          // d-row 0..63
  const int sgV = (lane & 7) ^ (lane >> 3);     // s-octet slot (XOR d&7)
  const u16* vgp = Vh + (size_t)dlV * 2048 + sgV * 8;
  const int vc = 4096 + w * 512;

  auto issue_tile = [&](int buf, int t) {
    u16* dst = lds + buf * 8192;
    const size_t k0 = (size_t)t * 64;
    async_load16(kgp + k0 * 1024, dst + kc);
    async_load16(vgp + k0, dst + vc);
  };

  issue_tile(0, 0);                    // tile 0 loads overlap Q-frag loads

  // Q fragments: 32 q-rows/wave (B-operand: col=lane&15, k-octet=quad)
  const int qbase = q0 + qq * 32;
  bf16x8 qf[2][2];
#pragma unroll
  for (int qt = 0; qt < 2; qt++)
#pragma unroll
    for (int ks = 0; ks < 2; ks++)
      qf[qt][ks] = *(const bf16x8*)(Qh + (size_t)(qbase + qt * 16 + (lane & 15)) * 1024 +
                                    ks * 32 + quad * 8);

  bf16x8 onesf;
#pragma unroll
  for (int i = 0; i < 8; i++) onesf[i] = (__bf16)1.0f;
  const floatx4 zero4 = {};

  // K-fragment LDS offsets: wave's s-half = rows sh*32..sh*32+31 (2 slabs);
  // row pitch 64 u16; octet slot XOR'd with s&7 (= lane&7 within slab).
  const int koff0 = (sh * 32 + (lane & 15)) * 64 + ((quad ^ (lane & 7)) * 8);
  const int koff1 = (sh * 32 + (lane & 15)) * 64 + (((4 + quad) ^ (lane & 7)) * 8);
  // V-fragment: PV k-octet quad holds s-octet (local-32) bitrev2(quad);
  // global-64 s-octet = sh*4 + sq; read slot = that ^ (d&7) (= lane&7).
  const int sq = ((quad & 1) << 1) | (quad >> 1);
  const int vslot = ((sh * 4 + sq) ^ (lane & 7)) * 8;

  floatx4 o[2][4] = {};
  floatx4 lacc[2] = {};              // partial row sums (this s-half)

  // drain qf + tile-0 staging once so the loop's vmcnt discipline is clean
  asm volatile("s_waitcnt vmcnt(0)" ::: "memory");

#pragma unroll 2
  for (int t = 0; t < 32; ++t) {
    __builtin_amdgcn_s_barrier();        // tile t visible to all waves
    __builtin_amdgcn_sched_barrier(0);
    if (t < 31) issue_tile((t + 1) & 1, t + 1);   // in flight across compute
    const u16* Ksb = lds + (t & 1) * 8192;
    const u16* Vsb = Ksb + 4096;

    // QK for this wave's 2 slabs (8 MFMAs batched)
    floatx4 st[2][2];
    __builtin_amdgcn_s_setprio(1);
#pragma unroll
    for (int si = 0; si < 2; si++) {
      bf16x8 kf0 = *(const bf16x8*)(Ksb + koff0 + si * 1024);
      bf16x8 kf1 = *(const bf16x8*)(Ksb + koff1 + si * 1024);
#pragma unroll
      for (int qt = 0; qt < 2; qt++)
        st[si][qt] = MFMA16(kf1, qf[qt][1], MFMA16(kf0, qf[qt][0], zero4));
    }
    __builtin_amdgcn_s_setprio(0);

    // p = exp2(st), pack to bf16 pairs
    unsigned pa[2][2], pb[2][2];
#pragma unroll
    for (int si = 0; si < 2; si++)
#pragma unroll
      for (int qt = 0; qt < 2; qt++) {
        pa[qt][si] = pack_bf2(fast_exp2(st[si][qt][0]), fast_exp2(st[si][qt][1]));
        pb[qt][si] = pack_bf2(fast_exp2(st[si][qt][2]), fast_exp2(st[si][qt][3]));
      }

    // in-register P->A-operand: swap quad pairs; k-octet order sigma=(0,2,1,3)
    bf16x8 pf[2];
#pragma unroll
    for (int qt = 0; qt < 2; qt++) {
      unsigned x0 = pa[qt][0], x1 = pa[qt][1];
      unsigned y0 = pb[qt][0], y1 = pb[qt][1];
      asm("v_permlane16_swap_b32 %0, %1" : "+v"(x0), "+v"(x1));
      asm("v_permlane16_swap_b32 %0, %1" : "+v"(y0), "+v"(y1));
      union { unsigned u[4]; bf16x8 v; } uu;
      uu.u[0] = x0; uu.u[1] = y0; uu.u[2] = x1; uu.u[3] = y1;
      pf[qt] = uu.v;
    }

    // O += P . V over this wave's 32-s half (one k=32 MFMA per d-tile)
    __builtin_amdgcn_s_setprio(1);
    bf16x8 vf[4];
#pragma unroll
    for (int jt = 0; jt < 4; jt++) {
      int d = jt * 16 + (lane & 15);
      vf[jt] = *(const bf16x8*)(Vsb + d * 64 + vslot);
    }
#pragma unroll
    for (int qt = 0; qt < 2; qt++) {
#pragma unroll
      for (int jt = 0; jt < 4; jt++)
        o[qt][jt] = MFMA16(pf[qt], vf[jt], o[qt][jt]);
      lacc[qt] = MFMA16(pf[qt], onesf, lacc[qt]);
    }
    __builtin_amdgcn_s_setprio(0);
    // own tile-(t+1) loads must be done before the next barrier
    asm volatile("s_waitcnt vmcnt(0)" ::: "memory");
  }

  // combine s-halves: sh==1 dumps O,l; sh==0 adds + stores.
  // dump region = lds[0..32KB) for O (2048 floatx4), [32KB..40KB) for l.
  __syncthreads();
  floatx4* dump  = (floatx4*)lds;
  floatx4* ldump = (floatx4*)(lds + 16384);
  if (sh == 1) {
    int base = qq * 512;
#pragma unroll
    for (int qt = 0; qt < 2; qt++)
#pragma unroll
      for (int jt = 0; jt < 4; jt++)
        dump[base + (qt * 4 + jt) * 64 + lane] = o[qt][jt];
#pragma unroll
    for (int qt = 0; qt < 2; qt++)
      ldump[qq * 128 + qt * 64 + lane] = lacc[qt];
  }
  __syncthreads();
  if (sh == 0) {
    int base = qq * 512;
#pragma unroll
    for (int qt = 0; qt < 2; qt++)
#pragma unroll
      for (int jt = 0; jt < 4; jt++)
        o[qt][jt] += dump[base + (qt * 4 + jt) * 64 + lane];
#pragma unroll
    for (int qt = 0; qt < 2; qt++)
      lacc[qt] += ldump[qq * 128 + qt * 64 + lane];
    // epilogue: ctx[b][s][h*64+d] bf16; lacc rows coincide with o rows
#pragma unroll
    for (int qt = 0; qt < 2; qt++)
#pragma unroll
      for (int r = 0; r < 4; r++) {
        float inv = 1.0f / lacc[qt][r];
        int s = qbase + qt * 16 + quad * 4 + r;
#pragma unroll
        for (int j = 0; j < 4; j++) {
          int c = h * 64 + j * 16 + (lane & 15);
          ctx[(size_t)(b * 2048 + s) * 1024 + c] = f2bf(o[qt][j][r] * inv);
        }
      }
  }
}

// ---- launch --------------------------------------------------------------
// ws layout (u16 elements, MM = 1024*1024):
//   [0,3MM)    WqT,WkT,WvT bf16        [3MM,4MM)  WoT bf16
//   [4MM,8MM)  x converted to bf16     [8MM,20MM) Q,K row-major (V slot unused)
//   [20MM,24MM) V^T bf16               [24MM,28MM) ctx bf16

extern "C" void kernel_launch(void* const* d_in, const int* in_sizes, int n_in,
                              void* d_out, int out_size, void* d_ws, size_t ws_size,
                              hipStream_t stream) {
  (void)in_sizes; (void)n_in; (void)out_size; (void)ws_size;
  const float* x  = (const float*)d_in[0];
  const float* Wq = (const float*)d_in[1];
  const float* Wk = (const float*)d_in[2];
  const float* Wv = (const float*)d_in[3];
  const float* Wo = (const float*)d_in[4];
  const float* bo = (const float*)d_in[5];
  u16* ws = (u16*)d_ws;
  const size_t MM = 1024 * 1024;
  u16* WT  = ws;             // 3 x [1024][1024] (Wq,Wk,Wv transposed)
  u16* WoT = ws + 3 * MM;    // [1024][1024]
  u16* Xb  = ws + 4 * MM;    // [4096][1024]
  u16* QKV = ws + 8 * MM;    // Q,K row-major [4096][1024] each
  u16* VTp = ws + 20 * MM;   // [32][64][2048]
  u16* CTX = ws + 24 * MM;   // [4096][1024]

  dim3 blk(256);
  prep_kernel<<<dim3(16, 16, 5), blk, 0, stream>>>(Wq, Wk, Wv, Wo, WT, x, Xb);
  gemm_qkv_kernel<<<dim3(16, 32, 1), blk, 0, stream>>>(Xb, WT, QKV, VTp);
  attn_kernel<<<dim3(512, 1, 1), dim3(512), 0, stream>>>(QKV, QKV + 4 * MM, VTp, CTX);
  gemm_o_kernel<<<dim3(16, 32, 1), blk, 0, stream>>>(CTX, WoT, bo, (float*)d_out);
}